// Round 3
// baseline (536.610 us; speedup 1.0000x reference)
//
#include <hip/hip_runtime.h>
#include <hip/hip_bf16.h>
#include <math.h>

// ---------------------------------------------------------------------------
// VariationalGATEncoder: 3x GATConv (single head, PyG semantics).
// Round 4 -> 5 change: XCD channel-sharded gathers.
//  R2/R3 established the gather wall: ~3.5-3.75 TB/s of L2-miss (fabric)
//  traffic, 57% L2 hit on random 512B rows of a 25.6MB table. Fix: shard
//  channels across XCDs. Block b handles slice s = b&7 (round-robin -> one
//  XCD per slice); slice table = 50K x 64B = 3.2MB fits 4MiB L2. Each XCD
//  streams the records (6.4MB) but row-gathers become L2 hits.
//  Wave layout: 4 edge-slots x 16 ch-pairs; 16-edge groups (4 rec + 4 row
//  loads in flight); 4 shfl_xor slot-reduce per node. alpha_cat now writes
//  two int2 record arrays (recM/recL) so each slice streams only its head.
// ---------------------------------------------------------------------------

#define NNODES 50000

typedef __attribute__((ext_vector_type(8))) short bf16x8;
typedef __attribute__((ext_vector_type(4))) float f32x4;

__device__ inline float bf2f(unsigned short u) {
    return __uint_as_float(((unsigned int)u) << 16);
}
__device__ inline unsigned short f2bf(float f) {
    unsigned int i = __float_as_uint(f);
    unsigned int r = i + 0x7fffu + ((i >> 16) & 1u);   // RNE
    return (unsigned short)(r >> 16);
}

// ---------------- converts ----------------

__global__ void f32_to_bf16_kernel(const float* __restrict__ in, unsigned short* __restrict__ out, int n4) {
    int i = blockIdx.x * blockDim.x + threadIdx.x;
    if (i < n4) {
        float4 v = ((const float4*)in)[i];
        ushort4 o;
        o.x = f2bf(v.x); o.y = f2bf(v.y); o.z = f2bf(v.z); o.w = f2bf(v.w);
        ((ushort4*)out)[i] = o;
    }
}

// Wt[n][k] = bf16(W[k][n]); W is [K x Nc] row-major. grid=Nc blocks, block=K threads.
__global__ void transpose_w_kernel(const float* __restrict__ W, unsigned short* __restrict__ Wt, int K, int Nc) {
    int n = blockIdx.x, k = threadIdx.x;
    Wt[(size_t)n * K + k] = f2bf(W[(size_t)k * Nc + n]);
}

// Wt (256 x 256): rows 0..127 = W_mu^T, rows 128..255 = W_ls^T. K=256, each head Nc=128.
__global__ void transpose_wcat_kernel(const float* __restrict__ Wmu, const float* __restrict__ Wls,
                                      unsigned short* __restrict__ Wt) {
    int n = blockIdx.x, k = threadIdx.x;
    float v = (n < 128) ? Wmu[(size_t)k * 128 + n] : Wls[(size_t)k * 128 + (n - 128)];
    Wt[(size_t)n * 256 + k] = f2bf(v);
}

// ---------------- CSR build ----------------

__global__ void count_edges(const int* __restrict__ dst, int E, int* __restrict__ cnt) {
    int e = blockIdx.x * blockDim.x + threadIdx.x;
    if (e < E) atomicAdd(&cnt[dst[e]], 1);
}

__global__ void scan_partial(const int* __restrict__ cnt, int* __restrict__ row_start,
                             int* __restrict__ bsum, int N) {
    __shared__ int wsum[16];
    int t = threadIdx.x;
    int gi = blockIdx.x * 1024 + t;
    int lane = t & 63, wid = t >> 6;
    int v = (gi < N) ? cnt[gi] : 0;
    int x = v;
    for (int off = 1; off < 64; off <<= 1) {
        int u = __shfl_up(x, off);
        if (lane >= off) x += u;
    }
    if (lane == 63) wsum[wid] = x;
    __syncthreads();
    if (wid == 0) {
        int s = (lane < 16) ? wsum[lane] : 0;
        for (int off = 1; off < 16; off <<= 1) {
            int u = __shfl_up(s, off);
            if (lane >= off) s += u;
        }
        if (lane < 16) wsum[lane] = s;
    }
    __syncthreads();
    int waveoff = (wid == 0) ? 0 : wsum[wid - 1];
    if (gi < N) row_start[gi] = waveoff + x - v;
    if (t == 1023) bsum[blockIdx.x] = waveoff + x;
}

__global__ void scan_bsum(int* __restrict__ bsum, int nb) {   // one wave, nb <= 64
    int lane = threadIdx.x;
    int v = (lane < nb) ? bsum[lane] : 0;
    int x = v;
    for (int off = 1; off < 64; off <<= 1) {
        int u = __shfl_up(x, off);
        if (lane >= off) x += u;
    }
    if (lane < nb) bsum[lane] = x - v;   // exclusive
}

__global__ void scan_add(int* __restrict__ row_start, const int* __restrict__ bsum, int N, int E) {
    int gi = blockIdx.x * 1024 + threadIdx.x;
    if (gi < N) row_start[gi] += bsum[blockIdx.x];
    if (gi == 0) row_start[N] = E;
}

__global__ void scatter_edges(const int* __restrict__ src, const int* __restrict__ dst, int E,
                              const int* __restrict__ row_start, int* __restrict__ cursor,
                              int* __restrict__ sperm) {
    int e = blockIdx.x * blockDim.x + threadIdx.x;
    if (e < E) {
        int d = dst[e];
        int pos = row_start[d] + atomicAdd(&cursor[d], 1);
        sperm[pos] = src[e];
    }
}

// ---------------- bf16 MFMA GEMM ----------------
// C[M,Cout](bf16) = A[M,K](bf16) @ Bt[Cout,K](bf16)^T, fp32 accumulate.
// 128x128 tile, BK=32, 256 threads (4 waves, 2x2 of 64x64 each).

__global__ __launch_bounds__(256) void mfma_gemm(const unsigned short* __restrict__ A,
                                                 const unsigned short* __restrict__ Bt,
                                                 unsigned short* __restrict__ C_,
                                                 int M, int K, int Cout) {
    __shared__ __align__(16) unsigned short As[128 * 40];  // rows padded to 40 (80B): 2-way max
    __shared__ __align__(16) unsigned short Bs[128 * 40];
    int t = threadIdx.x;
    int lane = t & 63, w = t >> 6;
    int wm = w & 1, wn = w >> 1;
    int l15 = lane & 15, quad = lane >> 4;
    int mbase = blockIdx.x * 128, nbase = blockIdx.y * 128;

    f32x4 acc[4][4];
    const f32x4 zero = {0.f, 0.f, 0.f, 0.f};
#pragma unroll
    for (int mt = 0; mt < 4; mt++)
#pragma unroll
        for (int nt = 0; nt < 4; nt++) acc[mt][nt] = zero;

    for (int k0 = 0; k0 < K; k0 += 32) {
#pragma unroll
        for (int i = t; i < 512; i += 256) {
            int row = i >> 2, seg = i & 3;
            int gr = mbase + row;
            float4 va = make_float4(0.f, 0.f, 0.f, 0.f);
            if (gr < M) va = *(const float4*)(A + (size_t)gr * K + k0 + seg * 8);
            *(float4*)(&As[row * 40 + seg * 8]) = va;
            float4 vb = *(const float4*)(Bt + (size_t)(nbase + row) * K + k0 + seg * 8);
            *(float4*)(&Bs[row * 40 + seg * 8]) = vb;
        }
        __syncthreads();
        bf16x8 af[4], bfr[4];
#pragma unroll
        for (int mt = 0; mt < 4; mt++)
            af[mt] = *(const bf16x8*)(&As[(wm * 64 + mt * 16 + l15) * 40 + quad * 8]);
#pragma unroll
        for (int nt = 0; nt < 4; nt++)
            bfr[nt] = *(const bf16x8*)(&Bs[(wn * 64 + nt * 16 + l15) * 40 + quad * 8]);
#pragma unroll
        for (int mt = 0; mt < 4; mt++)
#pragma unroll
            for (int nt = 0; nt < 4; nt++)
                acc[mt][nt] = __builtin_amdgcn_mfma_f32_16x16x32_bf16(af[mt], bfr[nt], acc[mt][nt], 0, 0, 0);
        __syncthreads();
    }
    // epilogue: C/D layout col=lane&15, row=quad*4+reg (m89-verified)
#pragma unroll
    for (int mt = 0; mt < 4; mt++) {
#pragma unroll
        for (int nt = 0; nt < 4; nt++) {
#pragma unroll
            for (int r = 0; r < 4; r++) {
                int m = mbase + wm * 64 + mt * 16 + quad * 4 + r;
                int n = nbase + wn * 64 + nt * 16 + l15;
                if (m < M) C_[(size_t)m * Cout + n] = f2bf(acc[mt][nt][r]);
            }
        }
    }
}

// ---------------- scores ----------------

__global__ __launch_bounds__(256) void scores_l1(const unsigned short* __restrict__ h,
                                                 const float* __restrict__ a_src,
                                                 const float* __restrict__ a_dst,
                                                 float* __restrict__ ssrc,
                                                 float* __restrict__ sdst, int N) {
    int wave = threadIdx.x >> 6, lane = threadIdx.x & 63;
    int row = blockIdx.x * 4 + wave;
    if (row >= N) return;
    ushort4 u = *(const ushort4*)(h + (size_t)row * 256 + lane * 4);
    float h0 = bf2f(u.x), h1 = bf2f(u.y), h2 = bf2f(u.z), h3 = bf2f(u.w);
    float4 av = ((const float4*)a_src)[lane];
    float4 dv = ((const float4*)a_dst)[lane];
    float ss = h0 * av.x + h1 * av.y + h2 * av.z + h3 * av.w;
    float sd = h0 * dv.x + h1 * dv.y + h2 * dv.z + h3 * dv.w;
    for (int off = 32; off; off >>= 1) {
        ss += __shfl_xor(ss, off);
        sd += __shfl_xor(sd, off);
    }
    if (lane == 0) {
        ssrc[row] = ss;
        sdst[row] = sd;
    }
}

// lanes 0..31 -> mu head (channels lane*4..+3), lanes 32..63 -> logstd head.
__global__ __launch_bounds__(256) void scores_cat(const unsigned short* __restrict__ hcat,
                                                  const float* __restrict__ a_src_mu, const float* __restrict__ a_dst_mu,
                                                  const float* __restrict__ a_src_ls, const float* __restrict__ a_dst_ls,
                                                  float* __restrict__ sm_s, float* __restrict__ sm_d,
                                                  float* __restrict__ sl_s, float* __restrict__ sl_d, int N) {
    int wave = threadIdx.x >> 6, lane = threadIdx.x & 63;
    int row = blockIdx.x * 4 + wave;
    if (row >= N) return;
    ushort4 u = *(const ushort4*)(hcat + (size_t)row * 256 + lane * 4);
    float h0 = bf2f(u.x), h1 = bf2f(u.y), h2 = bf2f(u.z), h3 = bf2f(u.w);
    bool isMu = lane < 32;
    const float* as = isMu ? a_src_mu : a_src_ls;
    const float* ad = isMu ? a_dst_mu : a_dst_ls;
    int c = (lane & 31) * 4;
    float4 av = *(const float4*)(as + c);
    float4 dv = *(const float4*)(ad + c);
    float ss = h0 * av.x + h1 * av.y + h2 * av.z + h3 * av.w;
    float sd = h0 * dv.x + h1 * dv.y + h2 * dv.z + h3 * dv.w;
    for (int off = 16; off; off >>= 1) {   // reduce within each 32-lane half
        ss += __shfl_xor(ss, off);
        sd += __shfl_xor(sd, off);
    }
    if ((lane & 31) == 0) {
        if (isMu) { sm_s[row] = ss; sm_d[row] = sd; }
        else      { sl_s[row] = ss; sl_d[row] = sd; }
    }
}

// ---------------- alpha precompute ----------------
// Wave per dst node: segment softmax over incoming edges, scores-only traffic.
// rec_l1[e] = {float alpha; int src} (int2); cat: recM/recL int2 per head.

__global__ __launch_bounds__(256) void alpha_l1(const float* __restrict__ ssrc,
                                                const float* __restrict__ sdst,
                                                const int* __restrict__ row_start,
                                                const int* __restrict__ sperm,
                                                int2* __restrict__ rec, int N) {
    int wave = threadIdx.x >> 6, lane = threadIdx.x & 63;
    int node = blockIdx.x * 4 + wave;
    if (node >= N) return;
    int begin = row_start[node], end = row_start[node + 1];
    int deg = end - begin;
    if (deg <= 0) return;
    float sd = sdst[node];
    if (deg <= 64) {                       // fast path (mean degree ~16)
        int idx = begin + lane;
        bool valid = lane < deg;
        int s = valid ? sperm[idx] : 0;
        float e = -INFINITY;
        if (valid) {
            float t = ssrc[s] + sd;
            e = (t > 0.f) ? t : 0.2f * t;
        }
        float m = e;
        for (int off = 32; off; off >>= 1) m = fmaxf(m, __shfl_xor(m, off));
        float p = valid ? __expf(e - m) : 0.f;
        float z = p;
        for (int off = 32; off; off >>= 1) z += __shfl_xor(z, off);
        if (valid) rec[idx] = make_int2(__float_as_int(p / (z + 1e-16f)), s);
    } else {                               // generic 3-pass (rare)
        float m = -INFINITY;
        for (int j0 = begin; j0 < end; j0 += 64) {
            int idx = j0 + lane;
            float e = -INFINITY;
            if (idx < end) {
                float t = ssrc[sperm[idx]] + sd;
                e = (t > 0.f) ? t : 0.2f * t;
            }
            for (int off = 32; off; off >>= 1) e = fmaxf(e, __shfl_xor(e, off));
            m = fmaxf(m, e);
        }
        float z = 0.f;
        for (int j0 = begin; j0 < end; j0 += 64) {
            int idx = j0 + lane;
            float p = 0.f;
            int s = 0;
            if (idx < end) {
                s = sperm[idx];
                float t = ssrc[s] + sd;
                float e = (t > 0.f) ? t : 0.2f * t;
                p = __expf(e - m);
                rec[idx] = make_int2(__float_as_int(p), s);
            }
            float ps = p;
            for (int off = 32; off; off >>= 1) ps += __shfl_xor(ps, off);
            z += ps;
        }
        float invz = 1.f / (z + 1e-16f);
        for (int j0 = begin; j0 < end; j0 += 64) {
            int idx = j0 + lane;
            if (idx < end) {
                int2 v = rec[idx];
                v.x = __float_as_int(__int_as_float(v.x) * invz);
                rec[idx] = v;
            }
        }
    }
}

__global__ __launch_bounds__(256) void alpha_cat(const float* __restrict__ sm_s, const float* __restrict__ sm_d,
                                                 const float* __restrict__ sl_s, const float* __restrict__ sl_d,
                                                 const int* __restrict__ row_start,
                                                 const int* __restrict__ sperm,
                                                 int2* __restrict__ recM, int2* __restrict__ recL, int N) {
    int wave = threadIdx.x >> 6, lane = threadIdx.x & 63;
    int node = blockIdx.x * 4 + wave;
    if (node >= N) return;
    int begin = row_start[node], end = row_start[node + 1];
    int deg = end - begin;
    if (deg <= 0) return;
    float sdm = sm_d[node], sdl = sl_d[node];
    if (deg <= 64) {
        int idx = begin + lane;
        bool valid = lane < deg;
        int s = valid ? sperm[idx] : 0;
        float eM = -INFINITY, eL = -INFINITY;
        if (valid) {
            float tM = sm_s[s] + sdm;
            eM = (tM > 0.f) ? tM : 0.2f * tM;
            float tL = sl_s[s] + sdl;
            eL = (tL > 0.f) ? tL : 0.2f * tL;
        }
        float mM = eM, mL = eL;
        for (int off = 32; off; off >>= 1) {
            mM = fmaxf(mM, __shfl_xor(mM, off));
            mL = fmaxf(mL, __shfl_xor(mL, off));
        }
        float pM = valid ? __expf(eM - mM) : 0.f;
        float pL = valid ? __expf(eL - mL) : 0.f;
        float zM = pM, zL = pL;
        for (int off = 32; off; off >>= 1) {
            zM += __shfl_xor(zM, off);
            zL += __shfl_xor(zL, off);
        }
        if (valid) {
            recM[idx] = make_int2(__float_as_int(pM / (zM + 1e-16f)), s);
            recL[idx] = make_int2(__float_as_int(pL / (zL + 1e-16f)), s);
        }
    } else {
        float mM = -INFINITY, mL = -INFINITY;
        for (int j0 = begin; j0 < end; j0 += 64) {
            int idx = j0 + lane;
            float eM = -INFINITY, eL = -INFINITY;
            if (idx < end) {
                int s = sperm[idx];
                float tM = sm_s[s] + sdm;
                eM = (tM > 0.f) ? tM : 0.2f * tM;
                float tL = sl_s[s] + sdl;
                eL = (tL > 0.f) ? tL : 0.2f * tL;
            }
            for (int off = 32; off; off >>= 1) {
                eM = fmaxf(eM, __shfl_xor(eM, off));
                eL = fmaxf(eL, __shfl_xor(eL, off));
            }
            mM = fmaxf(mM, eM);
            mL = fmaxf(mL, eL);
        }
        float zM = 0.f, zL = 0.f;
        for (int j0 = begin; j0 < end; j0 += 64) {
            int idx = j0 + lane;
            float pM = 0.f, pL = 0.f;
            int s = 0;
            if (idx < end) {
                s = sperm[idx];
                float tM = sm_s[s] + sdm;
                float eM = (tM > 0.f) ? tM : 0.2f * tM;
                float tL = sl_s[s] + sdl;
                float eL = (tL > 0.f) ? tL : 0.2f * tL;
                pM = __expf(eM - mM);
                pL = __expf(eL - mL);
                recM[idx] = make_int2(__float_as_int(pM), s);
                recL[idx] = make_int2(__float_as_int(pL), s);
            }
            float psM = pM, psL = pL;
            for (int off = 32; off; off >>= 1) {
                psM += __shfl_xor(psM, off);
                psL += __shfl_xor(psL, off);
            }
            zM += psM; zL += psL;
        }
        float izM = 1.f / (zM + 1e-16f), izL = 1.f / (zL + 1e-16f);
        for (int j0 = begin; j0 < end; j0 += 64) {
            int idx = j0 + lane;
            if (idx < end) {
                int2 vM = recM[idx];
                vM.x = __float_as_int(__int_as_float(vM.x) * izM);
                recM[idx] = vM;
                int2 vL = recL[idx];
                vL.x = __float_as_int(__int_as_float(vL.x) * izL);
                recL[idx] = vL;
            }
        }
    }
}

// ---------------- XCD channel-sharded gather ----------------
// grid.x = (N/16) * 8; slice s = blockIdx.x & 7 (consecutive blocks
// round-robin across XCDs -> all blocks of slice s land on one XCD; its
// 50K x 64B slice table fits 4MiB L2). g = blockIdx.x >> 3.
// Wave lane layout: slot = lane>>4 (4 edge slots), ch2 = lane&15 (2 ch each).
// One ushort2 load/lane gathers 4 edges' 64B slices per instruction.
// 16-edge groups: 4 rec loads then 4 row loads in flight. Tail branch-free
// (index clamped, alpha zeroed). Slot-reduce: 2 shfl_xor per channel.

__global__ __launch_bounds__(256) void gather_l1_shard(const unsigned short* __restrict__ h,
                                                       const int2* __restrict__ rec,
                                                       const int* __restrict__ row_start,
                                                       const float* __restrict__ bias,
                                                       unsigned short* __restrict__ out, int N) {
    int s = blockIdx.x & 7, g = blockIdx.x >> 3;
    int wave = threadIdx.x >> 6, lane = threadIdx.x & 63;
    int slot = lane >> 4, ch2 = lane & 15;
    int chbase = s * 32 + ch2 * 2;
    float b0 = bias[chbase], b1 = bias[chbase + 1];
    int nbase = g * 16 + wave * 4;
#pragma unroll
    for (int r = 0; r < 4; r++) {
        int node = nbase + r;
        if (node >= N) return;
        int begin = row_start[node], end = row_start[node + 1];
        float a0 = 0.f, a1 = 0.f;
        for (int j = begin; j < end; j += 16) {
            int2 rr[4];
#pragma unroll
            for (int q = 0; q < 4; q++) {
                int e = j + q * 4 + slot;
                rr[q] = rec[e < end ? e : end - 1];
            }
            ushort2 uu[4];
#pragma unroll
            for (int q = 0; q < 4; q++)
                uu[q] = *(const ushort2*)(h + (size_t)rr[q].y * 256 + chbase);
#pragma unroll
            for (int q = 0; q < 4; q++) {
                int e = j + q * 4 + slot;
                float p = (e < end) ? __int_as_float(rr[q].x) : 0.f;
                a0 += p * bf2f(uu[q].x);
                a1 += p * bf2f(uu[q].y);
            }
        }
        a0 += __shfl_xor(a0, 16); a0 += __shfl_xor(a0, 32);
        a1 += __shfl_xor(a1, 16); a1 += __shfl_xor(a1, 32);
        if (slot == 0) {
            ushort2 o;
            o.x = f2bf(fmaxf(a0 + b0, 0.f));
            o.y = f2bf(fmaxf(a1 + b1, 0.f));
            *(ushort2*)(out + (size_t)node * 256 + chbase) = o;
        }
    }
}

// cat: slices 0..3 read hcat cols 0..127 (mu, recM) -> out_mu; 4..7 -> ls/recL.
__global__ __launch_bounds__(256) void gather_cat_shard(const unsigned short* __restrict__ hcat,
                                                        const int2* __restrict__ recM,
                                                        const int2* __restrict__ recL,
                                                        const int* __restrict__ row_start,
                                                        const float* __restrict__ b_mu, const float* __restrict__ b_ls,
                                                        float* __restrict__ out_mu, float* __restrict__ out_ls, int N) {
    int s = blockIdx.x & 7, g = blockIdx.x >> 3;
    int wave = threadIdx.x >> 6, lane = threadIdx.x & 63;
    int slot = lane >> 4, ch2 = lane & 15;
    bool isMu = s < 4;
    const int2* rec = isMu ? recM : recL;
    int chb_t = s * 32 + ch2 * 2;            // hcat channel
    int chb_o = (s & 3) * 32 + ch2 * 2;      // output channel
    const float* bias = isMu ? b_mu : b_ls;
    float* outp = isMu ? out_mu : out_ls;
    float b0 = bias[chb_o], b1 = bias[chb_o + 1];
    int nbase = g * 16 + wave * 4;
#pragma unroll
    for (int r = 0; r < 4; r++) {
        int node = nbase + r;
        if (node >= N) return;
        int begin = row_start[node], end = row_start[node + 1];
        float a0 = 0.f, a1 = 0.f;
        for (int j = begin; j < end; j += 16) {
            int2 rr[4];
#pragma unroll
            for (int q = 0; q < 4; q++) {
                int e = j + q * 4 + slot;
                rr[q] = rec[e < end ? e : end - 1];
            }
            ushort2 uu[4];
#pragma unroll
            for (int q = 0; q < 4; q++)
                uu[q] = *(const ushort2*)(hcat + (size_t)rr[q].y * 256 + chb_t);
#pragma unroll
            for (int q = 0; q < 4; q++) {
                int e = j + q * 4 + slot;
                float p = (e < end) ? __int_as_float(rr[q].x) : 0.f;
                a0 += p * bf2f(uu[q].x);
                a1 += p * bf2f(uu[q].y);
            }
        }
        a0 += __shfl_xor(a0, 16); a0 += __shfl_xor(a0, 32);
        a1 += __shfl_xor(a1, 16); a1 += __shfl_xor(a1, 32);
        if (slot == 0) {
            float2 o = make_float2(a0 + b0, a1 + b1);
            *(float2*)(outp + (size_t)node * 128 + chb_o) = o;
        }
    }
}

// ---------------- launch ----------------

extern "C" void kernel_launch(void* const* d_in, const int* in_sizes, int n_in,
                              void* d_out, int out_size, void* d_ws, size_t ws_size,
                              hipStream_t stream) {
    const int N = NNODES;
    const float* x      = (const float*)d_in[0];
    const int*   ei     = (const int*)d_in[1];
    const int    E      = in_sizes[1] / 2;
    const int*   src    = ei;
    const int*   dst    = ei + E;
    const float* W1     = (const float*)d_in[2];
    const float* a_src1 = (const float*)d_in[3];
    const float* a_dst1 = (const float*)d_in[4];
    const float* b1     = (const float*)d_in[5];
    const float* W_mu   = (const float*)d_in[6];
    const float* a_src_mu = (const float*)d_in[7];
    const float* a_dst_mu = (const float*)d_in[8];
    const float* b_mu   = (const float*)d_in[9];
    const float* W_ls   = (const float*)d_in[10];
    const float* a_src_ls = (const float*)d_in[11];
    const float* a_dst_ls = (const float*)d_in[12];
    const float* b_ls   = (const float*)d_in[13];

    const size_t NM = (size_t)N * 256;   // 12.8M elems

    // workspace layout (16B-aligned blocks first)
    char* w = (char*)d_ws;
    unsigned short* xb   = (unsigned short*)w;              w += NM * 2;
    unsigned short* hlin = (unsigned short*)w;              w += NM * 2;
    unsigned short* h    = (unsigned short*)w;              w += NM * 2;
    unsigned short* hcat = (unsigned short*)w;              w += NM * 2;
    unsigned short* W1t  = (unsigned short*)w;              w += 256 * 256 * 2;
    unsigned short* Wct  = (unsigned short*)w;              w += 256 * 256 * 2;
    int2* rec1 = (int2*)w;     w += (size_t)E * 8;
    int2* recM = (int2*)w;     w += (size_t)E * 8;
    int2* recL = (int2*)w;     w += (size_t)E * 8;
    float* s1s = (float*)w;  w += N * 4;
    float* s1d = (float*)w;  w += N * 4;
    float* sms = (float*)w;  w += N * 4;
    float* smd = (float*)w;  w += N * 4;
    float* sls = (float*)w;  w += N * 4;
    float* sld = (float*)w;  w += N * 4;
    int* row_start = (int*)w;  w += (N + 1) * 4;
    int* cnt = (int*)w;        w += N * 4;
    int* bsum = (int*)w;       w += 64 * 4;
    int* sperm = (int*)w;      w += (size_t)E * 4;

    const int egrid = (E + 255) / 256;
    const int ngrid4 = (N + 3) / 4;               // 12500
    const int nb1024 = (N + 1023) / 1024;         // 49
    const int mtiles = (N + 127) / 128;           // 391
    const int shgrid = ((N + 15) / 16) * 8;       // 25000: (node-group, slice)

    // ---- converts ----
    f32_to_bf16_kernel<<<(int)((NM / 4 + 255) / 256), 256, 0, stream>>>(x, xb, (int)(NM / 4));
    transpose_w_kernel<<<256, 256, 0, stream>>>(W1, W1t, 256, 256);
    transpose_wcat_kernel<<<256, 256, 0, stream>>>(W_mu, W_ls, Wct);

    // ---- CSR build (once; shared by all 3 layers) ----
    hipMemsetAsync(cnt, 0, N * sizeof(int), stream);
    count_edges<<<egrid, 256, 0, stream>>>(dst, E, cnt);
    scan_partial<<<nb1024, 1024, 0, stream>>>(cnt, row_start, bsum, N);
    scan_bsum<<<1, 64, 0, stream>>>(bsum, nb1024);
    scan_add<<<nb1024, 1024, 0, stream>>>(row_start, bsum, N, E);
    hipMemsetAsync(cnt, 0, N * sizeof(int), stream);
    scatter_edges<<<egrid, 256, 0, stream>>>(src, dst, E, row_start, cnt, sperm);

    // ---- layer 1: x -> h (relu) ----
    mfma_gemm<<<dim3(mtiles, 2), 256, 0, stream>>>(xb, W1t, hlin, N, 256, 256);
    scores_l1<<<ngrid4, 256, 0, stream>>>(hlin, a_src1, a_dst1, s1s, s1d, N);
    alpha_l1<<<ngrid4, 256, 0, stream>>>(s1s, s1d, row_start, sperm, rec1, N);
    gather_l1_shard<<<shgrid, 256, 0, stream>>>(hlin, rec1, row_start, b1, h, N);

    // ---- fused mu/logstd head ----
    mfma_gemm<<<dim3(mtiles, 2), 256, 0, stream>>>(h, Wct, hcat, N, 256, 256);
    scores_cat<<<ngrid4, 256, 0, stream>>>(hcat, a_src_mu, a_dst_mu, a_src_ls, a_dst_ls,
                                           sms, smd, sls, sld, N);
    alpha_cat<<<ngrid4, 256, 0, stream>>>(sms, smd, sls, sld, row_start, sperm, recM, recL, N);
    float* out_mu = (float*)d_out;
    float* out_ls = out_mu + (size_t)N * 128;
    gather_cat_shard<<<shgrid, 256, 0, stream>>>(hcat, recM, recL, row_start, b_mu, b_ls,
                                                 out_mu, out_ls, N);
}

// Round 5
// 384.074 us; speedup vs baseline: 1.3972x; 1.3972x over previous
//
#include <hip/hip_runtime.h>
#include <hip/hip_bf16.h>
#include <math.h>

// ---------------------------------------------------------------------------
// VariationalGATEncoder: 3x GATConv (single head, PyG semantics).
// Round 6: R5 structure with the GEMM staging bug fixed.
//  R5 failed (NaN): only ONE global_load_lds per thread per buffer staged
//  half the 128x32 tile; rows 64..127 of As/Bs were uninitialized. Fix:
//  two copies per thread per buffer (chunks t and t+256 -> global rows
//  row and row+64, LDS bases w*1024 and 4096+w*1024 bytes).
//  Everything else as R5: in-loop-softmax aggregates with 8x-unrolled
//  gathers (at random-512B fabric roofline, FETCH ~= compulsory 177MB),
//  fused prep kernel, memsets folded into scan_add.
// ---------------------------------------------------------------------------

#define NNODES 50000

typedef __attribute__((ext_vector_type(8))) short bf16x8;
typedef __attribute__((ext_vector_type(4))) float f32x4;

__device__ inline float bf2f(unsigned short u) {
    return __uint_as_float(((unsigned int)u) << 16);
}
__device__ inline unsigned short f2bf(float f) {
    unsigned int i = __float_as_uint(f);
    unsigned int r = i + 0x7fffu + ((i >> 16) & 1u);   // RNE
    return (unsigned short)(r >> 16);
}

__device__ __forceinline__ void async_copy16(unsigned short* lds, const unsigned short* g) {
    __builtin_amdgcn_global_load_lds((const __attribute__((address_space(1))) void*)g,
                                     (__attribute__((address_space(3))) void*)lds,
                                     16, 0, 0);
}

// ---------------- fused prep: x->bf16, W1^T, Wcat^T, zero cnt ----------------
// grid = 12500 (convert) + 256 (W1t) + 256 (Wct) + 196 (cnt zero) = 13208.

__global__ __launch_bounds__(256) void prep_kernel(const float* __restrict__ x,
                                                   unsigned short* __restrict__ xb,
                                                   const float* __restrict__ W1,
                                                   unsigned short* __restrict__ W1t,
                                                   const float* __restrict__ Wmu,
                                                   const float* __restrict__ Wls,
                                                   unsigned short* __restrict__ Wct,
                                                   int* __restrict__ cnt, int N) {
    int b = blockIdx.x, t = threadIdx.x;
    if (b < 12500) {                       // 12500*256 = 3.2M float4 = 12.8M elems
        int i = b * 256 + t;
        float4 v = ((const float4*)x)[i];
        ushort4 o;
        o.x = f2bf(v.x); o.y = f2bf(v.y); o.z = f2bf(v.z); o.w = f2bf(v.w);
        ((ushort4*)xb)[i] = o;
    } else if (b < 12756) {                // W1t[n][k] = bf16(W1[k][n]), 256x256
        int n = b - 12500;
        W1t[(size_t)n * 256 + t] = f2bf(W1[(size_t)t * 256 + n]);
    } else if (b < 13012) {                // Wct rows 0..127 = Wmu^T, 128..255 = Wls^T
        int n = b - 12756;
        float v = (n < 128) ? Wmu[(size_t)t * 128 + n] : Wls[(size_t)t * 128 + (n - 128)];
        Wct[(size_t)n * 256 + t] = f2bf(v);
    } else {                               // zero cnt
        int i = (b - 13012) * 256 + t;
        if (i < N) cnt[i] = 0;
    }
}

// ---------------- CSR build ----------------

__global__ void count_edges(const int* __restrict__ dst, int E, int* __restrict__ cnt) {
    int e = blockIdx.x * blockDim.x + threadIdx.x;
    if (e < E) atomicAdd(&cnt[dst[e]], 1);
}

__global__ void scan_partial(const int* __restrict__ cnt, int* __restrict__ row_start,
                             int* __restrict__ bsum, int N) {
    __shared__ int wsum[16];
    int t = threadIdx.x;
    int gi = blockIdx.x * 1024 + t;
    int lane = t & 63, wid = t >> 6;
    int v = (gi < N) ? cnt[gi] : 0;
    int x = v;
    for (int off = 1; off < 64; off <<= 1) {
        int u = __shfl_up(x, off);
        if (lane >= off) x += u;
    }
    if (lane == 63) wsum[wid] = x;
    __syncthreads();
    if (wid == 0) {
        int s = (lane < 16) ? wsum[lane] : 0;
        for (int off = 1; off < 16; off <<= 1) {
            int u = __shfl_up(s, off);
            if (lane >= off) s += u;
        }
        if (lane < 16) wsum[lane] = s;
    }
    __syncthreads();
    int waveoff = (wid == 0) ? 0 : wsum[wid - 1];
    if (gi < N) row_start[gi] = waveoff + x - v;
    if (t == 1023) bsum[blockIdx.x] = waveoff + x;
}

__global__ void scan_bsum(int* __restrict__ bsum, int nb) {   // one wave, nb <= 64
    int lane = threadIdx.x;
    int v = (lane < nb) ? bsum[lane] : 0;
    int x = v;
    for (int off = 1; off < 64; off <<= 1) {
        int u = __shfl_up(x, off);
        if (lane >= off) x += u;
    }
    if (lane < nb) bsum[lane] = x - v;   // exclusive
}

// also zeroes cnt so scatter_edges can reuse it as the per-node cursor
__global__ void scan_add(int* __restrict__ row_start, const int* __restrict__ bsum,
                         int* __restrict__ cnt, int N, int E) {
    int gi = blockIdx.x * 1024 + threadIdx.x;
    if (gi < N) {
        row_start[gi] += bsum[blockIdx.x];
        cnt[gi] = 0;
    }
    if (gi == 0) row_start[N] = E;
}

__global__ void scatter_edges(const int* __restrict__ src, const int* __restrict__ dst, int E,
                              const int* __restrict__ row_start, int* __restrict__ cursor,
                              int* __restrict__ sperm) {
    int e = blockIdx.x * blockDim.x + threadIdx.x;
    if (e < E) {
        int d = dst[e];
        int pos = row_start[d] + atomicAdd(&cursor[d], 1);
        sperm[pos] = src[e];
    }
}

// ---------------- bf16 MFMA GEMM (m97 pattern) ----------------
// C[M,Cout](bf16) = A[M,K](bf16) @ Bt[Cout,K](bf16)^T, fp32 accumulate.
// 128x128 tile, BK=32, 256 threads (4 waves, 2x2 of 64x64 each).
// Staging: global_load_lds width-16, linear LDS. Tile = 512 16B-chunks;
// thread t covers chunks t and t+256 (rows t>>2 and 64+(t>>2), seg t&3).
// Chunk c lives at LDS byte 16c; wave w bases = w*1024 and 4096+w*1024
// (wave-uniform; HW adds lane*16). OOB m-rows read workspace garbage (no
// fault: buffers are followed by more workspace) and are masked at C-write.

__global__ __launch_bounds__(256) void mfma_gemm(const unsigned short* __restrict__ A,
                                                 const unsigned short* __restrict__ Bt,
                                                 unsigned short* __restrict__ C_,
                                                 int M, int K, int Cout) {
    __shared__ __align__(16) unsigned short As[128 * 32];
    __shared__ __align__(16) unsigned short Bs[128 * 32];
    int t = threadIdx.x;
    int lane = t & 63, w = t >> 6;
    int wm = w & 1, wn = w >> 1;
    int l15 = lane & 15, quad = lane >> 4;
    int mbase = blockIdx.x * 128, nbase = blockIdx.y * 128;
    int row = t >> 2, seg = t & 3;
    const unsigned short* gA  = A  + (size_t)(mbase + row) * K + seg * 8;
    const unsigned short* gA2 = gA + (size_t)64 * K;
    const unsigned short* gB  = Bt + (size_t)(nbase + row) * K + seg * 8;
    const unsigned short* gB2 = gB + (size_t)64 * K;
    unsigned short* ldsA  = &As[w * 512];          // chunks t      (rows 0..63)
    unsigned short* ldsA2 = &As[2048 + w * 512];   // chunks t+256  (rows 64..127)
    unsigned short* ldsB  = &Bs[w * 512];
    unsigned short* ldsB2 = &Bs[2048 + w * 512];

    f32x4 acc[4][4];
    const f32x4 zero = {0.f, 0.f, 0.f, 0.f};
#pragma unroll
    for (int mt = 0; mt < 4; mt++)
#pragma unroll
        for (int nt = 0; nt < 4; nt++) acc[mt][nt] = zero;

    for (int k0 = 0; k0 < K; k0 += 32) {
        async_copy16(ldsA,  gA  + k0);
        async_copy16(ldsA2, gA2 + k0);
        async_copy16(ldsB,  gB  + k0);
        async_copy16(ldsB2, gB2 + k0);
        __syncthreads();                   // compiler drains vmcnt before barrier
        bf16x8 af[4], bfr[4];
#pragma unroll
        for (int mt = 0; mt < 4; mt++)
            af[mt] = *(const bf16x8*)(&As[(wm * 64 + mt * 16 + l15) * 32 + quad * 8]);
#pragma unroll
        for (int nt = 0; nt < 4; nt++)
            bfr[nt] = *(const bf16x8*)(&Bs[(wn * 64 + nt * 16 + l15) * 32 + quad * 8]);
#pragma unroll
        for (int mt = 0; mt < 4; mt++)
#pragma unroll
            for (int nt = 0; nt < 4; nt++)
                acc[mt][nt] = __builtin_amdgcn_mfma_f32_16x16x32_bf16(af[mt], bfr[nt], acc[mt][nt], 0, 0, 0);
        __syncthreads();
    }
    // epilogue: C/D layout col=lane&15, row=quad*4+reg (m89-verified)
#pragma unroll
    for (int mt = 0; mt < 4; mt++) {
#pragma unroll
        for (int nt = 0; nt < 4; nt++) {
#pragma unroll
            for (int r = 0; r < 4; r++) {
                int m = mbase + wm * 64 + mt * 16 + quad * 4 + r;
                int n = nbase + wn * 64 + nt * 16 + l15;
                if (m < M) C_[(size_t)m * Cout + n] = f2bf(acc[mt][nt][r]);
            }
        }
    }
}

// ---------------- scores ----------------

__global__ __launch_bounds__(256) void scores_l1(const unsigned short* __restrict__ h,
                                                 const float* __restrict__ a_src,
                                                 const float* __restrict__ a_dst,
                                                 float* __restrict__ ssrc,
                                                 float* __restrict__ sdst, int N) {
    int wave = threadIdx.x >> 6, lane = threadIdx.x & 63;
    int row = blockIdx.x * 4 + wave;
    if (row >= N) return;
    ushort4 u = *(const ushort4*)(h + (size_t)row * 256 + lane * 4);
    float h0 = bf2f(u.x), h1 = bf2f(u.y), h2 = bf2f(u.z), h3 = bf2f(u.w);
    float4 av = ((const float4*)a_src)[lane];
    float4 dv = ((const float4*)a_dst)[lane];
    float ss = h0 * av.x + h1 * av.y + h2 * av.z + h3 * av.w;
    float sd = h0 * dv.x + h1 * dv.y + h2 * dv.z + h3 * dv.w;
    for (int off = 32; off; off >>= 1) {
        ss += __shfl_xor(ss, off);
        sd += __shfl_xor(sd, off);
    }
    if (lane == 0) {
        ssrc[row] = ss;
        sdst[row] = sd;
    }
}

// lanes 0..31 -> mu head (channels lane*4..+3), lanes 32..63 -> logstd head.
__global__ __launch_bounds__(256) void scores_cat(const unsigned short* __restrict__ hcat,
                                                  const float* __restrict__ a_src_mu, const float* __restrict__ a_dst_mu,
                                                  const float* __restrict__ a_src_ls, const float* __restrict__ a_dst_ls,
                                                  float* __restrict__ sm_s, float* __restrict__ sm_d,
                                                  float* __restrict__ sl_s, float* __restrict__ sl_d, int N) {
    int wave = threadIdx.x >> 6, lane = threadIdx.x & 63;
    int row = blockIdx.x * 4 + wave;
    if (row >= N) return;
    ushort4 u = *(const ushort4*)(hcat + (size_t)row * 256 + lane * 4);
    float h0 = bf2f(u.x), h1 = bf2f(u.y), h2 = bf2f(u.z), h3 = bf2f(u.w);
    bool isMu = lane < 32;
    const float* as = isMu ? a_src_mu : a_src_ls;
    const float* ad = isMu ? a_dst_mu : a_dst_ls;
    int c = (lane & 31) * 4;
    float4 av = *(const float4*)(as + c);
    float4 dv = *(const float4*)(ad + c);
    float ss = h0 * av.x + h1 * av.y + h2 * av.z + h3 * av.w;
    float sd = h0 * dv.x + h1 * dv.y + h2 * dv.z + h3 * dv.w;
    for (int off = 16; off; off >>= 1) {   // reduce within each 32-lane half
        ss += __shfl_xor(ss, off);
        sd += __shfl_xor(sd, off);
    }
    if ((lane & 31) == 0) {
        if (isMu) { sm_s[row] = ss; sm_d[row] = sd; }
        else      { sl_s[row] = ss; sl_d[row] = sd; }
    }
}

// ---------------- aggregation (best measured: in-loop softmax, 8x MLP) ------

__global__ __launch_bounds__(256) void aggregate_l1(const unsigned short* __restrict__ h,
                                                    const float* __restrict__ s_src,
                                                    const float* __restrict__ s_dst,
                                                    const int* __restrict__ row_start,
                                                    const int* __restrict__ sperm,
                                                    const float* __restrict__ bias,
                                                    unsigned short* __restrict__ out, int N) {
    int wave = threadIdx.x >> 6, lane = threadIdx.x & 63;
    int node = blockIdx.x * 4 + wave;
    if (node >= N) return;
    int begin = row_start[node], end = row_start[node + 1];
    float sd = s_dst[node];
    float m = -INFINITY, z = 0.f;
    float acc0 = 0.f, acc1 = 0.f, acc2 = 0.f, acc3 = 0.f;

    for (int j0 = begin; j0 < end; j0 += 64) {
        int idx = j0 + lane;
        bool valid = idx < end;
        int s = valid ? sperm[idx] : 0;
        float e = -INFINITY;
        if (valid) {
            float t = s_src[s] + sd;
            e = (t > 0.f) ? t : 0.2f * t;
        }
        float cm = e;
        for (int off = 32; off; off >>= 1) cm = fmaxf(cm, __shfl_xor(cm, off));
        float newm = fmaxf(m, cm);
        float scale = (m == -INFINITY) ? 0.f : __expf(m - newm);
        z *= scale;
        acc0 *= scale; acc1 *= scale; acc2 *= scale; acc3 *= scale;
        m = newm;
        float p = valid ? __expf(e - m) : 0.f;
        float ps = p;
        for (int off = 32; off; off >>= 1) ps += __shfl_xor(ps, off);
        z += ps;
        int cnt8 = (min(64, end - j0) + 7) & ~7;   // p=0,s=0 on padded lanes
        for (int t = 0; t < cnt8; t += 8) {
            float pt[8];
            int st[8];
#pragma unroll
            for (int i = 0; i < 8; i++) {
                pt[i] = __shfl(p, t + i);
                st[i] = __shfl(s, t + i);
            }
            ushort4 u[8];
#pragma unroll
            for (int i = 0; i < 8; i++)
                u[i] = *(const ushort4*)(h + (size_t)st[i] * 256 + lane * 4);
#pragma unroll
            for (int i = 0; i < 8; i++) {
                acc0 += pt[i] * bf2f(u[i].x);
                acc1 += pt[i] * bf2f(u[i].y);
                acc2 += pt[i] * bf2f(u[i].z);
                acc3 += pt[i] * bf2f(u[i].w);
            }
        }
    }
    float inv = 1.f / (z + 1e-16f);
    float4 bv = ((const float4*)bias)[lane];
    float o0 = fmaxf(acc0 * inv + bv.x, 0.f);
    float o1 = fmaxf(acc1 * inv + bv.y, 0.f);
    float o2 = fmaxf(acc2 * inv + bv.z, 0.f);
    float o3 = fmaxf(acc3 * inv + bv.w, 0.f);
    ushort4 o;
    o.x = f2bf(o0); o.y = f2bf(o1); o.z = f2bf(o2); o.w = f2bf(o3);
    *(ushort4*)(out + (size_t)node * 256 + lane * 4) = o;
}

// fused mu/logstd: lanes 0..31 accumulate mu channels, 32..63 logstd channels.
__global__ __launch_bounds__(256) void aggregate_cat(const unsigned short* __restrict__ hcat,
                                                     const float* __restrict__ sm_s, const float* __restrict__ sm_d,
                                                     const float* __restrict__ sl_s, const float* __restrict__ sl_d,
                                                     const int* __restrict__ row_start,
                                                     const int* __restrict__ sperm,
                                                     const float* __restrict__ b_mu, const float* __restrict__ b_ls,
                                                     float* __restrict__ out_mu, float* __restrict__ out_ls, int N) {
    int wave = threadIdx.x >> 6, lane = threadIdx.x & 63;
    int node = blockIdx.x * 4 + wave;
    if (node >= N) return;
    int begin = row_start[node], end = row_start[node + 1];
    float sdm = sm_d[node], sdl = sl_d[node];
    float mM = -INFINITY, zM = 0.f, mL = -INFINITY, zL = 0.f;
    float acc0 = 0.f, acc1 = 0.f, acc2 = 0.f, acc3 = 0.f;
    bool isMu = lane < 32;

    for (int j0 = begin; j0 < end; j0 += 64) {
        int idx = j0 + lane;
        bool valid = idx < end;
        int s = valid ? sperm[idx] : 0;
        float eM = -INFINITY, eL = -INFINITY;
        if (valid) {
            float tM = sm_s[s] + sdm;
            eM = (tM > 0.f) ? tM : 0.2f * tM;
            float tL = sl_s[s] + sdl;
            eL = (tL > 0.f) ? tL : 0.2f * tL;
        }
        float cmM = eM, cmL = eL;
        for (int off = 32; off; off >>= 1) {
            cmM = fmaxf(cmM, __shfl_xor(cmM, off));
            cmL = fmaxf(cmL, __shfl_xor(cmL, off));
        }
        float nmM = fmaxf(mM, cmM);
        float nmL = fmaxf(mL, cmL);
        float scM = (mM == -INFINITY) ? 0.f : __expf(mM - nmM);
        float scL = (mL == -INFINITY) ? 0.f : __expf(mL - nmL);
        zM *= scM; zL *= scL;
        mM = nmM; mL = nmL;
        float mysc = isMu ? scM : scL;
        acc0 *= mysc; acc1 *= mysc; acc2 *= mysc; acc3 *= mysc;
        float pM = valid ? __expf(eM - mM) : 0.f;
        float pL = valid ? __expf(eL - mL) : 0.f;
        float psM = pM, psL = pL;
        for (int off = 32; off; off >>= 1) {
            psM += __shfl_xor(psM, off);
            psL += __shfl_xor(psL, off);
        }
        zM += psM; zL += psL;
        int cnt8 = (min(64, end - j0) + 7) & ~7;   // pM=pL=0,s=0 on padded lanes
        for (int t = 0; t < cnt8; t += 8) {
            float pt[8];
            int st[8];
#pragma unroll
            for (int i = 0; i < 8; i++) {
                float a = __shfl(pM, t + i);
                float b = __shfl(pL, t + i);
                pt[i] = isMu ? a : b;
                st[i] = __shfl(s, t + i);
            }
            ushort4 u[8];
#pragma unroll
            for (int i = 0; i < 8; i++)
                u[i] = *(const ushort4*)(hcat + (size_t)st[i] * 256 + lane * 4);
#pragma unroll
            for (int i = 0; i < 8; i++) {
                acc0 += pt[i] * bf2f(u[i].x);
                acc1 += pt[i] * bf2f(u[i].y);
                acc2 += pt[i] * bf2f(u[i].z);
                acc3 += pt[i] * bf2f(u[i].w);
            }
        }
    }
    float inv = isMu ? (1.f / (zM + 1e-16f)) : (1.f / (zL + 1e-16f));
    int c = (lane & 31) * 4;
    float4 bv = *(const float4*)((isMu ? b_mu : b_ls) + c);
    float4 o = make_float4(acc0 * inv + bv.x, acc1 * inv + bv.y,
                           acc2 * inv + bv.z, acc3 * inv + bv.w);
    float* dstp = isMu ? (out_mu + (size_t)node * 128 + c) : (out_ls + (size_t)node * 128 + c);
    *(float4*)dstp = o;
}

// ---------------- launch ----------------

extern "C" void kernel_launch(void* const* d_in, const int* in_sizes, int n_in,
                              void* d_out, int out_size, void* d_ws, size_t ws_size,
                              hipStream_t stream) {
    const int N = NNODES;
    const float* x      = (const float*)d_in[0];
    const int*   ei     = (const int*)d_in[1];
    const int    E      = in_sizes[1] / 2;
    const int*   src    = ei;
    const int*   dst    = ei + E;
    const float* W1     = (const float*)d_in[2];
    const float* a_src1 = (const float*)d_in[3];
    const float* a_dst1 = (const float*)d_in[4];
    const float* b1     = (const float*)d_in[5];
    const float* W_mu   = (const float*)d_in[6];
    const float* a_src_mu = (const float*)d_in[7];
    const float* a_dst_mu = (const float*)d_in[8];
    const float* b_mu   = (const float*)d_in[9];
    const float* W_ls   = (const float*)d_in[10];
    const float* a_src_ls = (const float*)d_in[11];
    const float* a_dst_ls = (const float*)d_in[12];
    const float* b_ls   = (const float*)d_in[13];

    const size_t NM = (size_t)N * 256;   // 12.8M elems

    // workspace layout (16B-aligned blocks first)
    char* w = (char*)d_ws;
    unsigned short* xb   = (unsigned short*)w;              w += NM * 2;
    unsigned short* hlin = (unsigned short*)w;              w += NM * 2;
    unsigned short* h    = (unsigned short*)w;              w += NM * 2;
    unsigned short* hcat = (unsigned short*)w;              w += NM * 2;
    unsigned short* W1t  = (unsigned short*)w;              w += 256 * 256 * 2;
    unsigned short* Wct  = (unsigned short*)w;              w += 256 * 256 * 2;
    float* s1s = (float*)w;  w += N * 4;
    float* s1d = (float*)w;  w += N * 4;
    float* sms = (float*)w;  w += N * 4;
    float* smd = (float*)w;  w += N * 4;
    float* sls = (float*)w;  w += N * 4;
    float* sld = (float*)w;  w += N * 4;
    int* row_start = (int*)w;  w += (N + 1) * 4;
    int* cnt = (int*)w;        w += N * 4;
    int* bsum = (int*)w;       w += 64 * 4;
    int* sperm = (int*)w;      w += (size_t)E * 4;

    const int egrid = (E + 255) / 256;
    const int ngrid4 = (N + 3) / 4;               // 12500
    const int nb1024 = (N + 1023) / 1024;         // 49
    const int mtiles = (N + 127) / 128;           // 391
    const int prepgrid = 13012 + (N + 255) / 256; // 13208

    // ---- fused prep (converts + transposes + cnt zero) ----
    prep_kernel<<<prepgrid, 256, 0, stream>>>(x, xb, W1, W1t, W_mu, W_ls, Wct, cnt, N);

    // ---- CSR build (once; shared by all 3 layers) ----
    count_edges<<<egrid, 256, 0, stream>>>(dst, E, cnt);
    scan_partial<<<nb1024, 1024, 0, stream>>>(cnt, row_start, bsum, N);
    scan_bsum<<<1, 64, 0, stream>>>(bsum, nb1024);
    scan_add<<<nb1024, 1024, 0, stream>>>(row_start, bsum, cnt, N, E);
    scatter_edges<<<egrid, 256, 0, stream>>>(src, dst, E, row_start, cnt, sperm);

    // ---- layer 1: x -> h (relu) ----
    mfma_gemm<<<dim3(mtiles, 2), 256, 0, stream>>>(xb, W1t, hlin, N, 256, 256);
    scores_l1<<<ngrid4, 256, 0, stream>>>(hlin, a_src1, a_dst1, s1s, s1d, N);
    aggregate_l1<<<ngrid4, 256, 0, stream>>>(hlin, s1s, s1d, row_start, sperm, b1, h, N);

    // ---- fused mu/logstd head ----
    mfma_gemm<<<dim3(mtiles, 2), 256, 0, stream>>>(h, Wct, hcat, N, 256, 256);
    scores_cat<<<ngrid4, 256, 0, stream>>>(hcat, a_src_mu, a_dst_mu, a_src_ls, a_dst_ls,
                                           sms, smd, sls, sld, N);
    float* out_mu = (float*)d_out;
    float* out_ls = out_mu + (size_t)N * 128;
    aggregate_cat<<<ngrid4, 256, 0, stream>>>(hcat, sms, smd, sls, sld, row_start, sperm,
                                              b_mu, b_ls, out_mu, out_ls, N);
}

// Round 6
// 378.285 us; speedup vs baseline: 1.4185x; 1.0153x over previous
//
#include <hip/hip_runtime.h>
#include <hip/hip_bf16.h>
#include <math.h>

// ---------------------------------------------------------------------------
// VariationalGATEncoder: 3x GATConv (single head, PyG semantics).
// Round 7: dispatch-count attack (12 -> 9) + score-kernel elimination.
//  - scores_l1 / scores_cat FUSED into the mfma_gemm epilogue: per C-fragment
//    row, dot with a_src/a_dst (8 FMA), 16-lane shfl_xor reduce, atomicAdd
//    into the per-node score arrays (zeroed in prep). Removes 2 dispatches
//    and 51MB of hlin/hcat re-reads; scores now computed on unrounded fp32.
//    For the cat GEMM the column half (mu|ls) is block-uniform (nbase>>7)
//    and indexes concatenated a-vectors built in prep.
//  - scan_bsum merged into scan_add (each block redundantly wave-scans the
//    49-entry bsum): 1 fewer dispatch.
//  Aggregates unchanged: established at the random-512B fabric roofline
//  (~3.7 TB/s, FETCH ~= compulsory 177MB, confirmed by two structures).
// ---------------------------------------------------------------------------

#define NNODES 50000

typedef __attribute__((ext_vector_type(8))) short bf16x8;
typedef __attribute__((ext_vector_type(4))) float f32x4;

__device__ inline float bf2f(unsigned short u) {
    return __uint_as_float(((unsigned int)u) << 16);
}
__device__ inline unsigned short f2bf(float f) {
    unsigned int i = __float_as_uint(f);
    unsigned int r = i + 0x7fffu + ((i >> 16) & 1u);   // RNE
    return (unsigned short)(r >> 16);
}

__device__ __forceinline__ void async_copy16(unsigned short* lds, const unsigned short* g) {
    __builtin_amdgcn_global_load_lds((const __attribute__((address_space(1))) void*)g,
                                     (__attribute__((address_space(3))) void*)lds,
                                     16, 0, 0);
}

// ---------------- fused prep ----------------
// x->bf16 (12500), W1^T (256), Wcat^T (256), zero s-arrays+cnt (1368),
// acat_src (1), acat_dst (1).  grid = 14382.

__global__ __launch_bounds__(256) void prep_kernel(const float* __restrict__ x,
                                                   unsigned short* __restrict__ xb,
                                                   const float* __restrict__ W1,
                                                   unsigned short* __restrict__ W1t,
                                                   const float* __restrict__ Wmu,
                                                   const float* __restrict__ Wls,
                                                   unsigned short* __restrict__ Wct,
                                                   float* __restrict__ zbase,   // 6N floats (s-arrays)
                                                   int* __restrict__ cnt,
                                                   const float* __restrict__ a_src_mu,
                                                   const float* __restrict__ a_src_ls,
                                                   const float* __restrict__ a_dst_mu,
                                                   const float* __restrict__ a_dst_ls,
                                                   float* __restrict__ acat_src,
                                                   float* __restrict__ acat_dst,
                                                   int N) {
    int b = blockIdx.x, t = threadIdx.x;
    if (b < 12500) {                       // 12500*256 = 3.2M float4 = 12.8M elems
        int i = b * 256 + t;
        float4 v = ((const float4*)x)[i];
        ushort4 o;
        o.x = f2bf(v.x); o.y = f2bf(v.y); o.z = f2bf(v.z); o.w = f2bf(v.w);
        ((ushort4*)xb)[i] = o;
    } else if (b < 12756) {                // W1t[n][k] = bf16(W1[k][n]), 256x256
        int n = b - 12500;
        W1t[(size_t)n * 256 + t] = f2bf(W1[(size_t)t * 256 + n]);
    } else if (b < 13012) {                // Wct rows 0..127 = Wmu^T, 128..255 = Wls^T
        int n = b - 12756;
        float v = (n < 128) ? Wmu[(size_t)t * 128 + n] : Wls[(size_t)t * 128 + (n - 128)];
        Wct[(size_t)n * 256 + t] = f2bf(v);
    } else if (b < 14380) {                // zero 6N floats + N ints
        int i = (b - 13012) * 256 + t;
        if (i < 6 * N) zbase[i] = 0.f;
        else if (i < 7 * N) cnt[i - 6 * N] = 0;
    } else if (b == 14380) {               // acat_src = a_src_mu || a_src_ls
        acat_src[t] = (t < 128) ? a_src_mu[t] : a_src_ls[t - 128];
    } else {                               // acat_dst = a_dst_mu || a_dst_ls
        acat_dst[t] = (t < 128) ? a_dst_mu[t] : a_dst_ls[t - 128];
    }
}

// ---------------- CSR build ----------------

__global__ void count_edges(const int* __restrict__ dst, int E, int* __restrict__ cnt) {
    int e = blockIdx.x * blockDim.x + threadIdx.x;
    if (e < E) atomicAdd(&cnt[dst[e]], 1);
}

__global__ void scan_partial(const int* __restrict__ cnt, int* __restrict__ row_start,
                             int* __restrict__ bsum, int N) {
    __shared__ int wsum[16];
    int t = threadIdx.x;
    int gi = blockIdx.x * 1024 + t;
    int lane = t & 63, wid = t >> 6;
    int v = (gi < N) ? cnt[gi] : 0;
    int x = v;
    for (int off = 1; off < 64; off <<= 1) {
        int u = __shfl_up(x, off);
        if (lane >= off) x += u;
    }
    if (lane == 63) wsum[wid] = x;
    __syncthreads();
    if (wid == 0) {
        int s = (lane < 16) ? wsum[lane] : 0;
        for (int off = 1; off < 16; off <<= 1) {
            int u = __shfl_up(s, off);
            if (lane >= off) s += u;
        }
        if (lane < 16) wsum[lane] = s;
    }
    __syncthreads();
    int waveoff = (wid == 0) ? 0 : wsum[wid - 1];
    if (gi < N) row_start[gi] = waveoff + x - v;
    if (t == 1023) bsum[blockIdx.x] = waveoff + x;
}

// scan_add with bsum-scan folded in: wave 0 of every block redundantly
// exclusive-scans the (nb<=64)-entry bsum, publishes this block's offset via
// LDS. Also zeroes cnt (cursor for scatter) and sets row_start[N]=E.
__global__ void scan_add2(int* __restrict__ row_start, const int* __restrict__ bsum,
                          int* __restrict__ cnt, int N, int E, int nb) {
    __shared__ int sb;
    int t = threadIdx.x;
    if (t < 64) {
        int v = (t < nb) ? bsum[t] : 0;
        int x = v;
        for (int off = 1; off < 64; off <<= 1) {
            int u = __shfl_up(x, off);
            if (t >= off) x += u;
        }
        if (t == blockIdx.x) sb = x - v;   // exclusive prefix for this block
    }
    __syncthreads();
    int off = sb;
    int gi = blockIdx.x * 1024 + t;
    if (gi < N) {
        row_start[gi] += off;
        cnt[gi] = 0;
    }
    if (gi == 0) row_start[N] = E;
}

__global__ void scatter_edges(const int* __restrict__ src, const int* __restrict__ dst, int E,
                              const int* __restrict__ row_start, int* __restrict__ cursor,
                              int* __restrict__ sperm) {
    int e = blockIdx.x * blockDim.x + threadIdx.x;
    if (e < E) {
        int d = dst[e];
        int pos = row_start[d] + atomicAdd(&cursor[d], 1);
        sperm[pos] = src[e];
    }
}

// ---------------- bf16 MFMA GEMM (m97 pattern) + fused scores ----------------
// C[M,Cout](bf16) = A[M,K](bf16) @ Bt[Cout,K](bf16)^T, fp32 accumulate.
// 128x128 tile, BK=32, 256 threads (4 waves, 2x2 of 64x64 each).
// Staging: global_load_lds width-16, linear LDS; thread t covers chunks t and
// t+256 (rows t>>2, 64+(t>>2); seg t&3); wave bases w*1024 / 4096+w*1024 B.
// Epilogue additionally accumulates s_src[m] += C[m,:].av, s_dst[m] += C[m,:].adv
// via 16-lane shfl reduce + atomicAdd. halfsplit: target arrays offset by
// (nbase>>7)*Nn (cat GEMM: col half 0 = mu -> sms/smd, half 1 = ls -> sls/sld).

__global__ __launch_bounds__(256) void mfma_gemm(const unsigned short* __restrict__ A,
                                                 const unsigned short* __restrict__ Bt,
                                                 unsigned short* __restrict__ C_,
                                                 const float* __restrict__ av,
                                                 const float* __restrict__ adv,
                                                 float* __restrict__ s_src,
                                                 float* __restrict__ s_dst,
                                                 int halfsplit,
                                                 int M, int K, int Cout) {
    __shared__ __align__(16) unsigned short As[128 * 32];
    __shared__ __align__(16) unsigned short Bs[128 * 32];
    int t = threadIdx.x;
    int lane = t & 63, w = t >> 6;
    int wm = w & 1, wn = w >> 1;
    int l15 = lane & 15, quad = lane >> 4;
    int mbase = blockIdx.x * 128, nbase = blockIdx.y * 128;
    int row = t >> 2, seg = t & 3;
    const unsigned short* gA  = A  + (size_t)(mbase + row) * K + seg * 8;
    const unsigned short* gA2 = gA + (size_t)64 * K;
    const unsigned short* gB  = Bt + (size_t)(nbase + row) * K + seg * 8;
    const unsigned short* gB2 = gB + (size_t)64 * K;
    unsigned short* ldsA  = &As[w * 512];          // chunks t      (rows 0..63)
    unsigned short* ldsA2 = &As[2048 + w * 512];   // chunks t+256  (rows 64..127)
    unsigned short* ldsB  = &Bs[w * 512];
    unsigned short* ldsB2 = &Bs[2048 + w * 512];

    f32x4 acc[4][4];
    const f32x4 zero = {0.f, 0.f, 0.f, 0.f};
#pragma unroll
    for (int mt = 0; mt < 4; mt++)
#pragma unroll
        for (int nt = 0; nt < 4; nt++) acc[mt][nt] = zero;

    for (int k0 = 0; k0 < K; k0 += 32) {
        async_copy16(ldsA,  gA  + k0);
        async_copy16(ldsA2, gA2 + k0);
        async_copy16(ldsB,  gB  + k0);
        async_copy16(ldsB2, gB2 + k0);
        __syncthreads();                   // compiler drains vmcnt before barrier
        bf16x8 af[4], bfr[4];
#pragma unroll
        for (int mt = 0; mt < 4; mt++)
            af[mt] = *(const bf16x8*)(&As[(wm * 64 + mt * 16 + l15) * 32 + quad * 8]);
#pragma unroll
        for (int nt = 0; nt < 4; nt++)
            bfr[nt] = *(const bf16x8*)(&Bs[(wn * 64 + nt * 16 + l15) * 32 + quad * 8]);
#pragma unroll
        for (int mt = 0; mt < 4; mt++)
#pragma unroll
            for (int nt = 0; nt < 4; nt++)
                acc[mt][nt] = __builtin_amdgcn_mfma_f32_16x16x32_bf16(af[mt], bfr[nt], acc[mt][nt], 0, 0, 0);
        __syncthreads();
    }

    // attention vector elements for this lane's 4 column fragments
    float avr[4], advr[4];
#pragma unroll
    for (int nt = 0; nt < 4; nt++) {
        int n = nbase + wn * 64 + nt * 16 + l15;
        avr[nt]  = av[n];
        advr[nt] = adv[n];
    }
    float* ts = s_src + (halfsplit ? (size_t)(nbase >> 7) * M : 0);
    float* td = s_dst + (halfsplit ? (size_t)(nbase >> 7) * M : 0);

    // epilogue: C/D layout col=lane&15, row=quad*4+reg (m89-verified)
#pragma unroll
    for (int mt = 0; mt < 4; mt++) {
#pragma unroll
        for (int r = 0; r < 4; r++) {
            int m = mbase + wm * 64 + mt * 16 + quad * 4 + r;
            float vs = 0.f, vd = 0.f;
#pragma unroll
            for (int nt = 0; nt < 4; nt++) {
                float c = acc[mt][nt][r];
                vs += c * avr[nt];
                vd += c * advr[nt];
                int n = nbase + wn * 64 + nt * 16 + l15;
                if (m < M) C_[(size_t)m * Cout + n] = f2bf(c);
            }
            vs += __shfl_xor(vs, 1); vd += __shfl_xor(vd, 1);
            vs += __shfl_xor(vs, 2); vd += __shfl_xor(vd, 2);
            vs += __shfl_xor(vs, 4); vd += __shfl_xor(vd, 4);
            vs += __shfl_xor(vs, 8); vd += __shfl_xor(vd, 8);
            if (l15 == 0 && m < M) {
                atomicAdd(ts + m, vs);
                atomicAdd(td + m, vd);
            }
        }
    }
}

// ---------------- aggregation (best measured: in-loop softmax, 8x MLP) ------

__global__ __launch_bounds__(256) void aggregate_l1(const unsigned short* __restrict__ h,
                                                    const float* __restrict__ s_src,
                                                    const float* __restrict__ s_dst,
                                                    const int* __restrict__ row_start,
                                                    const int* __restrict__ sperm,
                                                    const float* __restrict__ bias,
                                                    unsigned short* __restrict__ out, int N) {
    int wave = threadIdx.x >> 6, lane = threadIdx.x & 63;
    int node = blockIdx.x * 4 + wave;
    if (node >= N) return;
    int begin = row_start[node], end = row_start[node + 1];
    float sd = s_dst[node];
    float m = -INFINITY, z = 0.f;
    float acc0 = 0.f, acc1 = 0.f, acc2 = 0.f, acc3 = 0.f;

    for (int j0 = begin; j0 < end; j0 += 64) {
        int idx = j0 + lane;
        bool valid = idx < end;
        int s = valid ? sperm[idx] : 0;
        float e = -INFINITY;
        if (valid) {
            float t = s_src[s] + sd;
            e = (t > 0.f) ? t : 0.2f * t;
        }
        float cm = e;
        for (int off = 32; off; off >>= 1) cm = fmaxf(cm, __shfl_xor(cm, off));
        float newm = fmaxf(m, cm);
        float scale = (m == -INFINITY) ? 0.f : __expf(m - newm);
        z *= scale;
        acc0 *= scale; acc1 *= scale; acc2 *= scale; acc3 *= scale;
        m = newm;
        float p = valid ? __expf(e - m) : 0.f;
        float ps = p;
        for (int off = 32; off; off >>= 1) ps += __shfl_xor(ps, off);
        z += ps;
        int cnt8 = (min(64, end - j0) + 7) & ~7;   // p=0,s=0 on padded lanes
        for (int t = 0; t < cnt8; t += 8) {
            float pt[8];
            int st[8];
#pragma unroll
            for (int i = 0; i < 8; i++) {
                pt[i] = __shfl(p, t + i);
                st[i] = __shfl(s, t + i);
            }
            ushort4 u[8];
#pragma unroll
            for (int i = 0; i < 8; i++)
                u[i] = *(const ushort4*)(h + (size_t)st[i] * 256 + lane * 4);
#pragma unroll
            for (int i = 0; i < 8; i++) {
                acc0 += pt[i] * bf2f(u[i].x);
                acc1 += pt[i] * bf2f(u[i].y);
                acc2 += pt[i] * bf2f(u[i].z);
                acc3 += pt[i] * bf2f(u[i].w);
            }
        }
    }
    float inv = 1.f / (z + 1e-16f);
    float4 bv = ((const float4*)bias)[lane];
    float o0 = fmaxf(acc0 * inv + bv.x, 0.f);
    float o1 = fmaxf(acc1 * inv + bv.y, 0.f);
    float o2 = fmaxf(acc2 * inv + bv.z, 0.f);
    float o3 = fmaxf(acc3 * inv + bv.w, 0.f);
    ushort4 o;
    o.x = f2bf(o0); o.y = f2bf(o1); o.z = f2bf(o2); o.w = f2bf(o3);
    *(ushort4*)(out + (size_t)node * 256 + lane * 4) = o;
}

// fused mu/logstd: lanes 0..31 accumulate mu channels, 32..63 logstd channels.
__global__ __launch_bounds__(256) void aggregate_cat(const unsigned short* __restrict__ hcat,
                                                     const float* __restrict__ sm_s, const float* __restrict__ sm_d,
                                                     const float* __restrict__ sl_s, const float* __restrict__ sl_d,
                                                     const int* __restrict__ row_start,
                                                     const int* __restrict__ sperm,
                                                     const float* __restrict__ b_mu, const float* __restrict__ b_ls,
                                                     float* __restrict__ out_mu, float* __restrict__ out_ls, int N) {
    int wave = threadIdx.x >> 6, lane = threadIdx.x & 63;
    int node = blockIdx.x * 4 + wave;
    if (node >= N) return;
    int begin = row_start[node], end = row_start[node + 1];
    float sdm = sm_d[node], sdl = sl_d[node];
    float mM = -INFINITY, zM = 0.f, mL = -INFINITY, zL = 0.f;
    float acc0 = 0.f, acc1 = 0.f, acc2 = 0.f, acc3 = 0.f;
    bool isMu = lane < 32;

    for (int j0 = begin; j0 < end; j0 += 64) {
        int idx = j0 + lane;
        bool valid = idx < end;
        int s = valid ? sperm[idx] : 0;
        float eM = -INFINITY, eL = -INFINITY;
        if (valid) {
            float tM = sm_s[s] + sdm;
            eM = (tM > 0.f) ? tM : 0.2f * tM;
            float tL = sl_s[s] + sdl;
            eL = (tL > 0.f) ? tL : 0.2f * tL;
        }
        float cmM = eM, cmL = eL;
        for (int off = 32; off; off >>= 1) {
            cmM = fmaxf(cmM, __shfl_xor(cmM, off));
            cmL = fmaxf(cmL, __shfl_xor(cmL, off));
        }
        float nmM = fmaxf(mM, cmM);
        float nmL = fmaxf(mL, cmL);
        float scM = (mM == -INFINITY) ? 0.f : __expf(mM - nmM);
        float scL = (mL == -INFINITY) ? 0.f : __expf(mL - nmL);
        zM *= scM; zL *= scL;
        mM = nmM; mL = nmL;
        float mysc = isMu ? scM : scL;
        acc0 *= mysc; acc1 *= mysc; acc2 *= mysc; acc3 *= mysc;
        float pM = valid ? __expf(eM - mM) : 0.f;
        float pL = valid ? __expf(eL - mL) : 0.f;
        float psM = pM, psL = pL;
        for (int off = 32; off; off >>= 1) {
            psM += __shfl_xor(psM, off);
            psL += __shfl_xor(psL, off);
        }
        zM += psM; zL += psL;
        int cnt8 = (min(64, end - j0) + 7) & ~7;   // pM=pL=0,s=0 on padded lanes
        for (int t = 0; t < cnt8; t += 8) {
            float pt[8];
            int st[8];
#pragma unroll
            for (int i = 0; i < 8; i++) {
                float a = __shfl(pM, t + i);
                float b = __shfl(pL, t + i);
                pt[i] = isMu ? a : b;
                st[i] = __shfl(s, t + i);
            }
            ushort4 u[8];
#pragma unroll
            for (int i = 0; i < 8; i++)
                u[i] = *(const ushort4*)(hcat + (size_t)st[i] * 256 + lane * 4);
#pragma unroll
            for (int i = 0; i < 8; i++) {
                acc0 += pt[i] * bf2f(u[i].x);
                acc1 += pt[i] * bf2f(u[i].y);
                acc2 += pt[i] * bf2f(u[i].z);
                acc3 += pt[i] * bf2f(u[i].w);
            }
        }
    }
    float inv = isMu ? (1.f / (zM + 1e-16f)) : (1.f / (zL + 1e-16f));
    int c = (lane & 31) * 4;
    float4 bv = *(const float4*)((isMu ? b_mu : b_ls) + c);
    float4 o = make_float4(acc0 * inv + bv.x, acc1 * inv + bv.y,
                           acc2 * inv + bv.z, acc3 * inv + bv.w);
    float* dstp = isMu ? (out_mu + (size_t)node * 128 + c) : (out_ls + (size_t)node * 128 + c);
    *(float4*)dstp = o;
}

// ---------------- launch ----------------

extern "C" void kernel_launch(void* const* d_in, const int* in_sizes, int n_in,
                              void* d_out, int out_size, void* d_ws, size_t ws_size,
                              hipStream_t stream) {
    const int N = NNODES;
    const float* x      = (const float*)d_in[0];
    const int*   ei     = (const int*)d_in[1];
    const int    E      = in_sizes[1] / 2;
    const int*   src    = ei;
    const int*   dst    = ei + E;
    const float* W1     = (const float*)d_in[2];
    const float* a_src1 = (const float*)d_in[3];
    const float* a_dst1 = (const float*)d_in[4];
    const float* b1     = (const float*)d_in[5];
    const float* W_mu   = (const float*)d_in[6];
    const float* a_src_mu = (const float*)d_in[7];
    const float* a_dst_mu = (const float*)d_in[8];
    const float* b_mu   = (const float*)d_in[9];
    const float* W_ls   = (const float*)d_in[10];
    const float* a_src_ls = (const float*)d_in[11];
    const float* a_dst_ls = (const float*)d_in[12];
    const float* b_ls   = (const float*)d_in[13];

    const size_t NM = (size_t)N * 256;   // 12.8M elems

    // workspace layout (16B-aligned blocks first)
    char* w = (char*)d_ws;
    unsigned short* xb   = (unsigned short*)w;              w += NM * 2;
    unsigned short* hlin = (unsigned short*)w;              w += NM * 2;
    unsigned short* h    = (unsigned short*)w;              w += NM * 2;
    unsigned short* hcat = (unsigned short*)w;              w += NM * 2;
    unsigned short* W1t  = (unsigned short*)w;              w += 256 * 256 * 2;
    unsigned short* Wct  = (unsigned short*)w;              w += 256 * 256 * 2;
    // score arrays: contiguous 6N floats; (sms,sls) and (smd,sld) adjacent for
    // the halfsplit epilogue (target = base + half*N).
    float* s1s = (float*)w;  w += N * 4;
    float* s1d = (float*)w;  w += N * 4;
    float* sms = (float*)w;  w += N * 4;
    float* sls = (float*)w;  w += N * 4;
    float* smd = (float*)w;  w += N * 4;
    float* sld = (float*)w;  w += N * 4;
    float* acat_src = (float*)w;  w += 256 * 4;
    float* acat_dst = (float*)w;  w += 256 * 4;
    int* row_start = (int*)w;  w += (N + 1) * 4;
    int* cnt = (int*)w;        w += N * 4;
    int* bsum = (int*)w;       w += 64 * 4;
    int* sperm = (int*)w;      w += (size_t)E * 4;

    const int egrid = (E + 255) / 256;
    const int ngrid4 = (N + 3) / 4;               // 12500
    const int nb1024 = (N + 1023) / 1024;         // 49
    const int mtiles = (N + 127) / 128;           // 391
    const int prepgrid = 14382;

    // ---- fused prep (converts + transposes + zero scores/cnt + acat) ----
    prep_kernel<<<prepgrid, 256, 0, stream>>>(x, xb, W1, W1t, W_mu, W_ls, Wct,
                                              s1s, cnt,
                                              a_src_mu, a_src_ls, a_dst_mu, a_dst_ls,
                                              acat_src, acat_dst, N);

    // ---- CSR build (once; shared by all 3 layers) ----
    count_edges<<<egrid, 256, 0, stream>>>(dst, E, cnt);
    scan_partial<<<nb1024, 1024, 0, stream>>>(cnt, row_start, bsum, N);
    scan_add2<<<nb1024, 1024, 0, stream>>>(row_start, bsum, cnt, N, E, nb1024);
    scatter_edges<<<egrid, 256, 0, stream>>>(src, dst, E, row_start, cnt, sperm);

    // ---- layer 1: x -> h (relu); scores fused in GEMM epilogue ----
    mfma_gemm<<<dim3(mtiles, 2), 256, 0, stream>>>(xb, W1t, hlin, a_src1, a_dst1,
                                                   s1s, s1d, 0, N, 256, 256);
    aggregate_l1<<<ngrid4, 256, 0, stream>>>(hlin, s1s, s1d, row_start, sperm, b1, h, N);

    // ---- fused mu/logstd head; scores fused (halfsplit) ----
    mfma_gemm<<<dim3(mtiles, 2), 256, 0, stream>>>(h, Wct, hcat, acat_src, acat_dst,
                                                   sms, smd, 1, N, 256, 256);
    float* out_mu = (float*)d_out;
    float* out_ls = out_mu + (size_t)N * 128;
    aggregate_cat<<<ngrid4, 256, 0, stream>>>(hcat, sms, smd, sls, sld, row_start, sperm,
                                              b_mu, b_ls, out_mu, out_ls, N);
}

// Round 8
// 362.174 us; speedup vs baseline: 1.4816x; 1.0445x over previous
//
#include <hip/hip_runtime.h>
#include <hip/hip_bf16.h>
#include <math.h>

// ---------------------------------------------------------------------------
// VariationalGATEncoder: 3x GATConv (single head, PyG semantics).
// Round 9: R8 with the LDS staging address bug fixed.
//  R8 failed (NaN): staging destinations written as (char*)As + w*512 --
//  byte offset half of the intended w*1024 (R6 used &As[w*512] in USHORT
//  units). Waves overlapped in LDS -> garbage operands -> NaN. Fixed with
//  ushort-unit pointer arithmetic throughout (bf16 A path, both B paths).
//  Structure as R8:
//  - 6 dispatches: prep, scatter_direct (single-pass bucket CSR, cap 64),
//    gemm1(f32-A), aggregate_l1, gemm2, aggregate_cat.
//  - scores fused in GEMM epilogues; single-strip softmax (deg<=64).
//  - Aggregates at the established random-512B fabric roofline.
// ---------------------------------------------------------------------------

#define NNODES 50000

typedef __attribute__((ext_vector_type(8))) short bf16x8;
typedef __attribute__((ext_vector_type(4))) float f32x4;

__device__ inline float bf2f(unsigned short u) {
    return __uint_as_float(((unsigned int)u) << 16);
}
__device__ inline unsigned short f2bf(float f) {
    unsigned int i = __float_as_uint(f);
    unsigned int r = i + 0x7fffu + ((i >> 16) & 1u);   // RNE
    return (unsigned short)(r >> 16);
}
__device__ inline unsigned short f2bf_hw(float f) {    // hw v_cvt, RNE
    __hip_bfloat16 h(f);
    return reinterpret_cast<__hip_bfloat16_raw&>(h).x;
}

__device__ __forceinline__ void async_copy16(void* lds, const void* g) {
    __builtin_amdgcn_global_load_lds((const __attribute__((address_space(1))) void*)g,
                                     (__attribute__((address_space(3))) void*)lds,
                                     16, 0, 0);
}

// ---------------- fused prep ----------------
// W1^T (256), Wcat^T (256), zero 6N f + N int (1368), acat_src/dst (2).
// grid = 1882.

__global__ __launch_bounds__(256) void prep_kernel(const float* __restrict__ W1,
                                                   unsigned short* __restrict__ W1t,
                                                   const float* __restrict__ Wmu,
                                                   const float* __restrict__ Wls,
                                                   unsigned short* __restrict__ Wct,
                                                   float* __restrict__ zbase,   // 6N floats
                                                   int* __restrict__ cnt,
                                                   const float* __restrict__ a_src_mu,
                                                   const float* __restrict__ a_src_ls,
                                                   const float* __restrict__ a_dst_mu,
                                                   const float* __restrict__ a_dst_ls,
                                                   float* __restrict__ acat_src,
                                                   float* __restrict__ acat_dst,
                                                   int N) {
    int b = blockIdx.x, t = threadIdx.x;
    if (b < 256) {                         // W1t[n][k] = bf16(W1[k][n])
        int n = b;
        W1t[(size_t)n * 256 + t] = f2bf(W1[(size_t)t * 256 + n]);
    } else if (b < 512) {                  // Wct rows 0..127 = Wmu^T, 128..255 = Wls^T
        int n = b - 256;
        float v = (n < 128) ? Wmu[(size_t)t * 128 + n] : Wls[(size_t)t * 128 + (n - 128)];
        Wct[(size_t)n * 256 + t] = f2bf(v);
    } else if (b < 1880) {                 // zero 6N floats + N ints
        int i = (b - 512) * 256 + t;
        if (i < 6 * N) zbase[i] = 0.f;
        else if (i < 7 * N) cnt[i - 6 * N] = 0;
    } else if (b == 1880) {
        acat_src[t] = (t < 128) ? a_src_mu[t] : a_src_ls[t - 128];
    } else {
        acat_dst[t] = (t < 128) ? a_dst_mu[t] : a_dst_ls[t - 128];
    }
}

// ---------------- single-pass bucket build ----------------
// bucket[d*64 + pos] = src(e). cnt ends as degree. Order within bucket
// is arbitrary (sum is order-invariant).

__global__ void scatter_direct(const int* __restrict__ src, const int* __restrict__ dst,
                               int E, int* __restrict__ cnt, int* __restrict__ bucket) {
    int e = blockIdx.x * blockDim.x + threadIdx.x;
    if (e < E) {
        int d = dst[e];
        int pos = atomicAdd(&cnt[d], 1);
        if (pos < 64) bucket[(d << 6) + pos] = src[e];
    }
}

// ---------------- bf16 MFMA GEMM (m97 pattern) + fused scores ----------------
// C[M,Cout](bf16) = A[M,K] @ Bt[Cout,K](bf16)^T, fp32 accumulate.
// 128x128 tile, BK=32, 256 threads (4 waves, 2x2 of 64x64 each).
// Linear LDS, chunk c (16B) at ushort offset 512*wave + ... (HW adds lane*16B;
// ALL offsets in USHORT units: +512 = 1024B per wave, +2048 = 4096B half-tile).
// AF32: A f32, 4 copies/thread into 16KB tile, frags hw-cvt'd after ds_read.
// Global rows clamped to M-1 (OOB-safe); garbage rows masked at C/score write.
// Epilogue: C-write + s_src/s_dst dot (16-lane shfl reduce) + atomicAdd.
// halfsplit: score target offset by (nbase>>7)*M (cat: half0=mu, half1=ls).

template <bool AF32>
__global__ __launch_bounds__(256) void mfma_gemm(const void* __restrict__ Araw,
                                                 const unsigned short* __restrict__ Bt,
                                                 unsigned short* __restrict__ C_,
                                                 const float* __restrict__ av,
                                                 const float* __restrict__ adv,
                                                 float* __restrict__ s_src,
                                                 float* __restrict__ s_dst,
                                                 int halfsplit,
                                                 int M, int K, int Cout) {
    __shared__ __align__(16) unsigned short As[AF32 ? 128 * 64 : 128 * 32];
    __shared__ __align__(16) unsigned short Bs[128 * 32];
    int t = threadIdx.x;
    int lane = t & 63, w = t >> 6;
    int wm = w & 1, wn = w >> 1;
    int l15 = lane & 15, quad = lane >> 4;
    int mbase = blockIdx.x * 128, nbase = blockIdx.y * 128;
    int row = t >> 2, seg = t & 3;

    // B staging pointers (bf16): chunks t (rows 0..63) and t+256 (rows 64..127)
    const unsigned short* gB  = Bt + (size_t)(nbase + row) * K + seg * 8;
    const unsigned short* gB2 = gB + (size_t)64 * K;
    // A staging pointers (bf16 path)
    const unsigned short* gA = nullptr; const unsigned short* gA2 = nullptr;
    if constexpr (!AF32) {
        const unsigned short* Ab = (const unsigned short*)Araw;
        int gr  = min(mbase + row, M - 1);
        int gr2 = min(mbase + row + 64, M - 1);
        gA  = Ab + (size_t)gr  * K + seg * 8;
        gA2 = Ab + (size_t)gr2 * K + seg * 8;
    }

    f32x4 acc[4][4];
    const f32x4 zero = {0.f, 0.f, 0.f, 0.f};
#pragma unroll
    for (int mt = 0; mt < 4; mt++)
#pragma unroll
        for (int nt = 0; nt < 4; nt++) acc[mt][nt] = zero;

    for (int k0 = 0; k0 < K; k0 += 32) {
        if constexpr (AF32) {
            const float* Af = (const float*)Araw;
#pragma unroll
            for (int i = 0; i < 4; i++) {
                int c = t + (i << 8);              // chunk index 0..1023
                int r = c >> 3, sg = c & 7;        // 8 chunks (32 f32) per row
                int gr = min(mbase + r, M - 1);
                // chunk c at byte 16c = 1024*w + 16*lane + 4096*i
                async_copy16(As + w * 512 + i * 2048,          // ushort units
                             Af + (size_t)gr * K + sg * 4 + k0);
            }
        } else {
            async_copy16(As + w * 512,        gA + k0);        // bytes w*1024
            async_copy16(As + 2048 + w * 512, gA2 + k0);       // bytes 4096+w*1024
        }
        async_copy16(Bs + w * 512,        gB + k0);
        async_copy16(Bs + 2048 + w * 512, gB2 + k0);
        __syncthreads();                   // compiler drains vmcnt before barrier

        bf16x8 af[4], bfr[4];
#pragma unroll
        for (int mt = 0; mt < 4; mt++) {
            int arow = wm * 64 + mt * 16 + l15;
            if constexpr (AF32) {
                const float* Afl = (const float*)As;
                float4 lo = *(const float4*)(Afl + arow * 32 + quad * 8);
                float4 hi = *(const float4*)(Afl + arow * 32 + quad * 8 + 4);
                union { bf16x8 v; unsigned short u[8]; } cu;
                cu.u[0] = f2bf_hw(lo.x); cu.u[1] = f2bf_hw(lo.y);
                cu.u[2] = f2bf_hw(lo.z); cu.u[3] = f2bf_hw(lo.w);
                cu.u[4] = f2bf_hw(hi.x); cu.u[5] = f2bf_hw(hi.y);
                cu.u[6] = f2bf_hw(hi.z); cu.u[7] = f2bf_hw(hi.w);
                af[mt] = cu.v;
            } else {
                af[mt] = *(const bf16x8*)(&As[arow * 32 + quad * 8]);
            }
        }
#pragma unroll
        for (int nt = 0; nt < 4; nt++)
            bfr[nt] = *(const bf16x8*)(&Bs[(wn * 64 + nt * 16 + l15) * 32 + quad * 8]);
#pragma unroll
        for (int mt = 0; mt < 4; mt++)
#pragma unroll
            for (int nt = 0; nt < 4; nt++)
                acc[mt][nt] = __builtin_amdgcn_mfma_f32_16x16x32_bf16(af[mt], bfr[nt], acc[mt][nt], 0, 0, 0);
        __syncthreads();
    }

    // attention vector elements for this lane's 4 column fragments
    float avr[4], advr[4];
#pragma unroll
    for (int nt = 0; nt < 4; nt++) {
        int n = nbase + wn * 64 + nt * 16 + l15;
        avr[nt]  = av[n];
        advr[nt] = adv[n];
    }
    float* ts = s_src + (halfsplit ? (size_t)(nbase >> 7) * M : 0);
    float* td = s_dst + (halfsplit ? (size_t)(nbase >> 7) * M : 0);

    // epilogue: C/D layout col=lane&15, row=quad*4+reg (m89-verified)
#pragma unroll
    for (int mt = 0; mt < 4; mt++) {
#pragma unroll
        for (int r = 0; r < 4; r++) {
            int m = mbase + wm * 64 + mt * 16 + quad * 4 + r;
            float vs = 0.f, vd = 0.f;
#pragma unroll
            for (int nt = 0; nt < 4; nt++) {
                float c = acc[mt][nt][r];
                vs += c * avr[nt];
                vd += c * advr[nt];
                int n = nbase + wn * 64 + nt * 16 + l15;
                if (m < M) C_[(size_t)m * Cout + n] = f2bf(c);
            }
            vs += __shfl_xor(vs, 1); vd += __shfl_xor(vd, 1);
            vs += __shfl_xor(vs, 2); vd += __shfl_xor(vd, 2);
            vs += __shfl_xor(vs, 4); vd += __shfl_xor(vd, 4);
            vs += __shfl_xor(vs, 8); vd += __shfl_xor(vd, 8);
            if (l15 == 0 && m < M) {
                atomicAdd(ts + m, vs);
                atomicAdd(td + m, vd);
            }
        }
    }
}

// ---------------- aggregation (single-strip softmax, 8x-unrolled gather) ----
// Wave per dst node; deg <= 64 guaranteed by bucket capacity.

__global__ __launch_bounds__(256) void aggregate_l1(const unsigned short* __restrict__ h,
                                                    const float* __restrict__ s_src,
                                                    const float* __restrict__ s_dst,
                                                    const int* __restrict__ cnt,
                                                    const int* __restrict__ bucket,
                                                    const float* __restrict__ bias,
                                                    unsigned short* __restrict__ out, int N) {
    int wave = threadIdx.x >> 6, lane = threadIdx.x & 63;
    int node = blockIdx.x * 4 + wave;
    if (node >= N) return;
    int deg = min(cnt[node], 64);
    int base = node << 6;
    float sd = s_dst[node];
    bool valid = lane < deg;
    int s = valid ? bucket[base + lane] : 0;
    float e = -INFINITY;
    if (valid) {
        float t = s_src[s] + sd;
        e = (t > 0.f) ? t : 0.2f * t;
    }
    float m = e;
    for (int off = 32; off; off >>= 1) m = fmaxf(m, __shfl_xor(m, off));
    float p = valid ? __expf(e - m) : 0.f;
    float z = p;
    for (int off = 32; off; off >>= 1) z += __shfl_xor(z, off);

    float acc0 = 0.f, acc1 = 0.f, acc2 = 0.f, acc3 = 0.f;
    int cnt8 = (deg + 7) & ~7;             // p=0,s=0 on padded lanes
    for (int t0 = 0; t0 < cnt8; t0 += 8) {
        float pt[8];
        int st[8];
#pragma unroll
        for (int i = 0; i < 8; i++) {
            pt[i] = __shfl(p, t0 + i);
            st[i] = __shfl(s, t0 + i);
        }
        ushort4 u[8];
#pragma unroll
        for (int i = 0; i < 8; i++)
            u[i] = *(const ushort4*)(h + (size_t)st[i] * 256 + lane * 4);
#pragma unroll
        for (int i = 0; i < 8; i++) {
            acc0 += pt[i] * bf2f(u[i].x);
            acc1 += pt[i] * bf2f(u[i].y);
            acc2 += pt[i] * bf2f(u[i].z);
            acc3 += pt[i] * bf2f(u[i].w);
        }
    }
    float inv = 1.f / (z + 1e-16f);
    float4 bv = ((const float4*)bias)[lane];
    ushort4 o;
    o.x = f2bf(fmaxf(acc0 * inv + bv.x, 0.f));
    o.y = f2bf(fmaxf(acc1 * inv + bv.y, 0.f));
    o.z = f2bf(fmaxf(acc2 * inv + bv.z, 0.f));
    o.w = f2bf(fmaxf(acc3 * inv + bv.w, 0.f));
    *(ushort4*)(out + (size_t)node * 256 + lane * 4) = o;
}

// fused mu/logstd: lanes 0..31 accumulate mu channels, 32..63 logstd channels.
__global__ __launch_bounds__(256) void aggregate_cat(const unsigned short* __restrict__ hcat,
                                                     const float* __restrict__ sm_s, const float* __restrict__ sm_d,
                                                     const float* __restrict__ sl_s, const float* __restrict__ sl_d,
                                                     const int* __restrict__ cnt,
                                                     const int* __restrict__ bucket,
                                                     const float* __restrict__ b_mu, const float* __restrict__ b_ls,
                                                     float* __restrict__ out_mu, float* __restrict__ out_ls, int N) {
    int wave = threadIdx.x >> 6, lane = threadIdx.x & 63;
    int node = blockIdx.x * 4 + wave;
    if (node >= N) return;
    int deg = min(cnt[node], 64);
    int base = node << 6;
    float sdm = sm_d[node], sdl = sl_d[node];
    bool isMu = lane < 32;
    bool valid = lane < deg;
    int s = valid ? bucket[base + lane] : 0;
    float eM = -INFINITY, eL = -INFINITY;
    if (valid) {
        float tM = sm_s[s] + sdm;
        eM = (tM > 0.f) ? tM : 0.2f * tM;
        float tL = sl_s[s] + sdl;
        eL = (tL > 0.f) ? tL : 0.2f * tL;
    }
    float mM = eM, mL = eL;
    for (int off = 32; off; off >>= 1) {
        mM = fmaxf(mM, __shfl_xor(mM, off));
        mL = fmaxf(mL, __shfl_xor(mL, off));
    }
    float pM = valid ? __expf(eM - mM) : 0.f;
    float pL = valid ? __expf(eL - mL) : 0.f;
    float zM = pM, zL = pL;
    for (int off = 32; off; off >>= 1) {
        zM += __shfl_xor(zM, off);
        zL += __shfl_xor(zL, off);
    }

    float acc0 = 0.f, acc1 = 0.f, acc2 = 0.f, acc3 = 0.f;
    int cnt8 = (deg + 7) & ~7;
    for (int t0 = 0; t0 < cnt8; t0 += 8) {
        float pt[8];
        int st[8];
#pragma unroll
        for (int i = 0; i < 8; i++) {
            float a = __shfl(pM, t0 + i);
            float b = __shfl(pL, t0 + i);
            pt[i] = isMu ? a : b;
            st[i] = __shfl(s, t0 + i);
        }
        ushort4 u[8];
#pragma unroll
        for (int i = 0; i < 8; i++)
            u[i] = *(const ushort4*)(hcat + (size_t)st[i] * 256 + lane * 4);
#pragma unroll
        for (int i = 0; i < 8; i++) {
            acc0 += pt[i] * bf2f(u[i].x);
            acc1 += pt[i] * bf2f(u[i].y);
            acc2 += pt[i] * bf2f(u[i].z);
            acc3 += pt[i] * bf2f(u[i].w);
        }
    }
    float inv = isMu ? (1.f / (zM + 1e-16f)) : (1.f / (zL + 1e-16f));
    int c = (lane & 31) * 4;
    float4 bv = *(const float4*)((isMu ? b_mu : b_ls) + c);
    float4 o = make_float4(acc0 * inv + bv.x, acc1 * inv + bv.y,
                           acc2 * inv + bv.z, acc3 * inv + bv.w);
    float* dstp = isMu ? (out_mu + (size_t)node * 128 + c) : (out_ls + (size_t)node * 128 + c);
    *(float4*)dstp = o;
}

// ---------------- launch ----------------

extern "C" void kernel_launch(void* const* d_in, const int* in_sizes, int n_in,
                              void* d_out, int out_size, void* d_ws, size_t ws_size,
                              hipStream_t stream) {
    const int N = NNODES;
    const float* x      = (const float*)d_in[0];
    const int*   ei     = (const int*)d_in[1];
    const int    E      = in_sizes[1] / 2;
    const int*   src    = ei;
    const int*   dst    = ei + E;
    const float* W1     = (const float*)d_in[2];
    const float* a_src1 = (const float*)d_in[3];
    const float* a_dst1 = (const float*)d_in[4];
    const float* b1     = (const float*)d_in[5];
    const float* W_mu   = (const float*)d_in[6];
    const float* a_src_mu = (const float*)d_in[7];
    const float* a_dst_mu = (const float*)d_in[8];
    const float* b_mu   = (const float*)d_in[9];
    const float* W_ls   = (const float*)d_in[10];
    const float* a_src_ls = (const float*)d_in[11];
    const float* a_dst_ls = (const float*)d_in[12];
    const float* b_ls   = (const float*)d_in[13];

    const size_t NM = (size_t)N * 256;   // 12.8M elems

    // workspace layout (16B-aligned blocks first)
    char* w = (char*)d_ws;
    unsigned short* hlin = (unsigned short*)w;              w += NM * 2;
    unsigned short* h    = (unsigned short*)w;              w += NM * 2;
    unsigned short* hcat = (unsigned short*)w;              w += NM * 2;
    unsigned short* W1t  = (unsigned short*)w;              w += 256 * 256 * 2;
    unsigned short* Wct  = (unsigned short*)w;              w += 256 * 256 * 2;
    // score arrays: contiguous 6N floats; (sms,sls) and (smd,sld) adjacent for
    // the halfsplit epilogue (target = base + half*N).
    float* s1s = (float*)w;  w += N * 4;
    float* s1d = (float*)w;  w += N * 4;
    float* sms = (float*)w;  w += N * 4;
    float* sls = (float*)w;  w += N * 4;
    float* smd = (float*)w;  w += N * 4;
    float* sld = (float*)w;  w += N * 4;
    float* acat_src = (float*)w;  w += 256 * 4;
    float* acat_dst = (float*)w;  w += 256 * 4;
    int* cnt = (int*)w;        w += N * 4;
    int* bucket = (int*)w;     w += (size_t)N * 64 * 4;   // 12.8MB

    const int egrid = (E + 255) / 256;
    const int ngrid4 = (N + 3) / 4;               // 12500
    const int mtiles = (N + 127) / 128;           // 391

    // ---- fused prep (W transposes + zero scores/cnt + acat) ----
    prep_kernel<<<1882, 256, 0, stream>>>(W1, W1t, W_mu, W_ls, Wct,
                                          s1s, cnt,
                                          a_src_mu, a_src_ls, a_dst_mu, a_dst_ls,
                                          acat_src, acat_dst, N);

    // ---- bucket build (single pass) ----
    scatter_direct<<<egrid, 256, 0, stream>>>(src, dst, E, cnt, bucket);

    // ---- layer 1: x -> h (relu); scores fused in GEMM epilogue ----
    mfma_gemm<true><<<dim3(mtiles, 2), 256, 0, stream>>>(x, W1t, hlin, a_src1, a_dst1,
                                                         s1s, s1d, 0, N, 256, 256);
    aggregate_l1<<<ngrid4, 256, 0, stream>>>(hlin, s1s, s1d, cnt, bucket, b1, h, N);

    // ---- fused mu/logstd head; scores fused (halfsplit) ----
    mfma_gemm<false><<<dim3(mtiles, 2), 256, 0, stream>>>(h, Wct, hcat, acat_src, acat_dst,
                                                          sms, smd, 1, N, 256, 256);
    float* out_mu = (float*)d_out;
    float* out_ls = out_mu + (size_t)N * 128;
    aggregate_cat<<<ngrid4, 256, 0, stream>>>(hcat, sms, smd, sls, sld, cnt, bucket,
                                              b_mu, b_ls, out_mu, out_ls, N);
}

// Round 9
// 333.089 us; speedup vs baseline: 1.6110x; 1.0873x over previous
//
#include <hip/hip_runtime.h>
#include <hip/hip_bf16.h>
#include <math.h>

// ---------------------------------------------------------------------------
// VariationalGATEncoder: 3x GATConv (single head, PyG semantics).
// Round 10: fix gemm1's LDS bank conflicts (R9 profile: mfma_gemm<AF32> top
// at 68us, SQ_LDS_BANK_CONFLICT=1.78e7, MfmaUtil 3.5%).
//  Cause: A-f32 tile rows are 128B -> fragment ds_read_b128 slots depend only
//  on quad (4 slots, 16 lanes/slot = 2x the 8-lane/slot HW floor).
//  Fix (rule #21, both-sides-or-neither): involution chunk swizzle
//  phys = c ^ ((c>>3)&7). Staging keeps linear global_load_lds dest and
//  pre-swizzles the GLOBAL source segment; frag read XORs with arow&7.
//  B / gemm2-A tiles (64B rows) already sit at the 8-slot floor - untouched.
//  Everything else as R9 (6 dispatches, bucket CSR, fused scores,
//  aggregates at the random-512B fabric roofline).
// ---------------------------------------------------------------------------

#define NNODES 50000

typedef __attribute__((ext_vector_type(8))) short bf16x8;
typedef __attribute__((ext_vector_type(4))) float f32x4;

__device__ inline float bf2f(unsigned short u) {
    return __uint_as_float(((unsigned int)u) << 16);
}
__device__ inline unsigned short f2bf(float f) {
    unsigned int i = __float_as_uint(f);
    unsigned int r = i + 0x7fffu + ((i >> 16) & 1u);   // RNE
    return (unsigned short)(r >> 16);
}
__device__ inline unsigned short f2bf_hw(float f) {    // hw v_cvt, RNE
    __hip_bfloat16 h(f);
    return reinterpret_cast<__hip_bfloat16_raw&>(h).x;
}

__device__ __forceinline__ void async_copy16(void* lds, const void* g) {
    __builtin_amdgcn_global_load_lds((const __attribute__((address_space(1))) void*)g,
                                     (__attribute__((address_space(3))) void*)lds,
                                     16, 0, 0);
}

// ---------------- fused prep ----------------
// W1^T (256), Wcat^T (256), zero 6N f + N int (1368), acat_src/dst (2).
// grid = 1882.

__global__ __launch_bounds__(256) void prep_kernel(const float* __restrict__ W1,
                                                   unsigned short* __restrict__ W1t,
                                                   const float* __restrict__ Wmu,
                                                   const float* __restrict__ Wls,
                                                   unsigned short* __restrict__ Wct,
                                                   float* __restrict__ zbase,   // 6N floats
                                                   int* __restrict__ cnt,
                                                   const float* __restrict__ a_src_mu,
                                                   const float* __restrict__ a_src_ls,
                                                   const float* __restrict__ a_dst_mu,
                                                   const float* __restrict__ a_dst_ls,
                                                   float* __restrict__ acat_src,
                                                   float* __restrict__ acat_dst,
                                                   int N) {
    int b = blockIdx.x, t = threadIdx.x;
    if (b < 256) {                         // W1t[n][k] = bf16(W1[k][n])
        int n = b;
        W1t[(size_t)n * 256 + t] = f2bf(W1[(size_t)t * 256 + n]);
    } else if (b < 512) {                  // Wct rows 0..127 = Wmu^T, 128..255 = Wls^T
        int n = b - 256;
        float v = (n < 128) ? Wmu[(size_t)t * 128 + n] : Wls[(size_t)t * 128 + (n - 128)];
        Wct[(size_t)n * 256 + t] = f2bf(v);
    } else if (b < 1880) {                 // zero 6N floats + N ints
        int i = (b - 512) * 256 + t;
        if (i < 6 * N) zbase[i] = 0.f;
        else if (i < 7 * N) cnt[i - 6 * N] = 0;
    } else if (b == 1880) {
        acat_src[t] = (t < 128) ? a_src_mu[t] : a_src_ls[t - 128];
    } else {
        acat_dst[t] = (t < 128) ? a_dst_mu[t] : a_dst_ls[t - 128];
    }
}

// ---------------- single-pass bucket build ----------------
// bucket[d*64 + pos] = src(e). cnt ends as degree. Order within bucket
// is arbitrary (sum is order-invariant).

__global__ void scatter_direct(const int* __restrict__ src, const int* __restrict__ dst,
                               int E, int* __restrict__ cnt, int* __restrict__ bucket) {
    int e = blockIdx.x * blockDim.x + threadIdx.x;
    if (e < E) {
        int d = dst[e];
        int pos = atomicAdd(&cnt[d], 1);
        if (pos < 64) bucket[(d << 6) + pos] = src[e];
    }
}

// ---------------- bf16 MFMA GEMM (m97 pattern) + fused scores ----------------
// C[M,Cout](bf16) = A[M,K] @ Bt[Cout,K](bf16)^T, fp32 accumulate.
// 128x128 tile, BK=32, 256 threads (4 waves, 2x2 of 64x64 each).
// Linear LDS; chunk c (16B) at ushort offset 8c; wave-uniform staging bases
// in USHORT units (+512/wave = 1024B, +2048 = 4096B).
// AF32: A f32 [128][32]f32 tile (128B rows). Chunk SWIZZLE phys=c^((c>>3)&7)
// (involution, XOR bits3-5 into 0-2): staging pre-swizzles the GLOBAL source
// segment (linear LDS dest), frag read XORs chunk with arow&7. This spreads
// the frag ds_read_b128 from 4 slots/16-lane pile-up to the 8-slot HW floor.
// B / bf16-A tiles (64B rows) are already at the floor: no swizzle.
// Global rows clamped to M-1 (OOB-safe); garbage rows masked at C/score write.
// Epilogue: C-write + s_src/s_dst dot (16-lane shfl reduce) + atomicAdd.
// halfsplit: score target offset by (nbase>>7)*M (cat: half0=mu, half1=ls).

template <bool AF32>
__global__ __launch_bounds__(256) void mfma_gemm(const void* __restrict__ Araw,
                                                 const unsigned short* __restrict__ Bt,
                                                 unsigned short* __restrict__ C_,
                                                 const float* __restrict__ av,
                                                 const float* __restrict__ adv,
                                                 float* __restrict__ s_src,
                                                 float* __restrict__ s_dst,
                                                 int halfsplit,
                                                 int M, int K, int Cout) {
    __shared__ __align__(16) unsigned short As[AF32 ? 128 * 64 : 128 * 32];
    __shared__ __align__(16) unsigned short Bs[128 * 32];
    int t = threadIdx.x;
    int lane = t & 63, w = t >> 6;
    int wm = w & 1, wn = w >> 1;
    int l15 = lane & 15, quad = lane >> 4;
    int mbase = blockIdx.x * 128, nbase = blockIdx.y * 128;
    int row = t >> 2, seg = t & 3;

    // B staging pointers (bf16): chunks t (rows 0..63) and t+256 (rows 64..127)
    const unsigned short* gB  = Bt + (size_t)(nbase + row) * K + seg * 8;
    const unsigned short* gB2 = gB + (size_t)64 * K;
    // A staging pointers
    const unsigned short* gA = nullptr; const unsigned short* gA2 = nullptr;
    const float* gAf0 = nullptr; const float* gAf1 = nullptr;
    const float* gAf2 = nullptr; const float* gAf3 = nullptr;
    if constexpr (AF32) {
        const float* Af = (const float*)Araw;
        // dest chunk d = t + i*256 holds logical chunk l = d ^ ((d>>3)&7)
        // (involution). l -> row l>>3, 16B-seg l&7.
        int d0 = t,        l0 = d0 ^ ((d0 >> 3) & 7);
        int d1 = t + 256,  l1 = d1 ^ ((d1 >> 3) & 7);
        int d2 = t + 512,  l2 = d2 ^ ((d2 >> 3) & 7);
        int d3 = t + 768,  l3 = d3 ^ ((d3 >> 3) & 7);
        gAf0 = Af + (size_t)min(mbase + (l0 >> 3), M - 1) * K + (l0 & 7) * 4;
        gAf1 = Af + (size_t)min(mbase + (l1 >> 3), M - 1) * K + (l1 & 7) * 4;
        gAf2 = Af + (size_t)min(mbase + (l2 >> 3), M - 1) * K + (l2 & 7) * 4;
        gAf3 = Af + (size_t)min(mbase + (l3 >> 3), M - 1) * K + (l3 & 7) * 4;
    } else {
        const unsigned short* Ab = (const unsigned short*)Araw;
        int gr  = min(mbase + row, M - 1);
        int gr2 = min(mbase + row + 64, M - 1);
        gA  = Ab + (size_t)gr  * K + seg * 8;
        gA2 = Ab + (size_t)gr2 * K + seg * 8;
    }

    f32x4 acc[4][4];
    const f32x4 zero = {0.f, 0.f, 0.f, 0.f};
#pragma unroll
    for (int mt = 0; mt < 4; mt++)
#pragma unroll
        for (int nt = 0; nt < 4; nt++) acc[mt][nt] = zero;

    for (int k0 = 0; k0 < K; k0 += 32) {
        if constexpr (AF32) {
            async_copy16(As + w * 512,        gAf0 + k0);   // chunks t
            async_copy16(As + 2048 + w * 512, gAf1 + k0);   // chunks t+256
            async_copy16(As + 4096 + w * 512, gAf2 + k0);   // chunks t+512
            async_copy16(As + 6144 + w * 512, gAf3 + k0);   // chunks t+768
        } else {
            async_copy16(As + w * 512,        gA + k0);
            async_copy16(As + 2048 + w * 512, gA2 + k0);
        }
        async_copy16(Bs + w * 512,        gB + k0);
        async_copy16(Bs + 2048 + w * 512, gB2 + k0);
        __syncthreads();                   // compiler drains vmcnt before barrier

        bf16x8 af[4], bfr[4];
#pragma unroll
        for (int mt = 0; mt < 4; mt++) {
            int arow = wm * 64 + mt * 16 + l15;
            if constexpr (AF32) {
                const float* Afl = (const float*)As;
                int a7 = arow & 7;
                int cl = arow * 8 + quad * 2;      // logical chunk of lo float4
                float4 lo = *(const float4*)(Afl + (size_t)((cl    ) ^ a7) * 4);
                float4 hi = *(const float4*)(Afl + (size_t)((cl + 1) ^ a7) * 4);
                union { bf16x8 v; unsigned short u[8]; } cu;
                cu.u[0] = f2bf_hw(lo.x); cu.u[1] = f2bf_hw(lo.y);
                cu.u[2] = f2bf_hw(lo.z); cu.u[3] = f2bf_hw(lo.w);
                cu.u[4] = f2bf_hw(hi.x); cu.u[5] = f2bf_hw(hi.y);
                cu.u[6] = f2bf_hw(hi.z); cu.u[7] = f2bf_hw(hi.w);
                af[mt] = cu.v;
            } else {
                af[mt] = *(const bf16x8*)(&As[arow * 32 + quad * 8]);
            }
        }
#pragma unroll
        for (int nt = 0; nt < 4; nt++)
            bfr[nt] = *(const bf16x8*)(&Bs[(wn * 64 + nt * 16 + l15) * 32 + quad * 8]);
#pragma unroll
        for (int mt = 0; mt < 4; mt++)
#pragma unroll
            for (int nt = 0; nt < 4; nt++)
                acc[mt][nt] = __builtin_amdgcn_mfma_f32_16x16x32_bf16(af[mt], bfr[nt], acc[mt][nt], 0, 0, 0);
        __syncthreads();
    }

    // attention vector elements for this lane's 4 column fragments
    float avr[4], advr[4];
#pragma unroll
    for (int nt = 0; nt < 4; nt++) {
        int n = nbase + wn * 64 + nt * 16 + l15;
        avr[nt]  = av[n];
        advr[nt] = adv[n];
    }
    float* ts = s_src + (halfsplit ? (size_t)(nbase >> 7) * M : 0);
    float* td = s_dst + (halfsplit ? (size_t)(nbase >> 7) * M : 0);

    // epilogue: C/D layout col=lane&15, row=quad*4+reg (m89-verified)
#pragma unroll
    for (int mt = 0; mt < 4; mt++) {
#pragma unroll
        for (int r = 0; r < 4; r++) {
            int m = mbase + wm * 64 + mt * 16 + quad * 4 + r;
            float vs = 0.f, vd = 0.f;
#pragma unroll
            for (int nt = 0; nt < 4; nt++) {
                float c = acc[mt][nt][r];
                vs += c * avr[nt];
                vd += c * advr[nt];
                int n = nbase + wn * 64 + nt * 16 + l15;
                if (m < M) C_[(size_t)m * Cout + n] = f2bf(c);
            }
            vs += __shfl_xor(vs, 1); vd += __shfl_xor(vd, 1);
            vs += __shfl_xor(vs, 2); vd += __shfl_xor(vd, 2);
            vs += __shfl_xor(vs, 4); vd += __shfl_xor(vd, 4);
            vs += __shfl_xor(vs, 8); vd += __shfl_xor(vd, 8);
            if (l15 == 0 && m < M) {
                atomicAdd(ts + m, vs);
                atomicAdd(td + m, vd);
            }
        }
    }
}

// ---------------- aggregation (single-strip softmax, 8x-unrolled gather) ----
// Wave per dst node; deg <= 64 guaranteed by bucket capacity.

__global__ __launch_bounds__(256) void aggregate_l1(const unsigned short* __restrict__ h,
                                                    const float* __restrict__ s_src,
                                                    const float* __restrict__ s_dst,
                                                    const int* __restrict__ cnt,
                                                    const int* __restrict__ bucket,
                                                    const float* __restrict__ bias,
                                                    unsigned short* __restrict__ out, int N) {
    int wave = threadIdx.x >> 6, lane = threadIdx.x & 63;
    int node = blockIdx.x * 4 + wave;
    if (node >= N) return;
    int deg = min(cnt[node], 64);
    int base = node << 6;
    float sd = s_dst[node];
    bool valid = lane < deg;
    int s = valid ? bucket[base + lane] : 0;
    float e = -INFINITY;
    if (valid) {
        float t = s_src[s] + sd;
        e = (t > 0.f) ? t : 0.2f * t;
    }
    float m = e;
    for (int off = 32; off; off >>= 1) m = fmaxf(m, __shfl_xor(m, off));
    float p = valid ? __expf(e - m) : 0.f;
    float z = p;
    for (int off = 32; off; off >>= 1) z += __shfl_xor(z, off);

    float acc0 = 0.f, acc1 = 0.f, acc2 = 0.f, acc3 = 0.f;
    int cnt8 = (deg + 7) & ~7;             // p=0,s=0 on padded lanes
    for (int t0 = 0; t0 < cnt8; t0 += 8) {
        float pt[8];
        int st[8];
#pragma unroll
        for (int i = 0; i < 8; i++) {
            pt[i] = __shfl(p, t0 + i);
            st[i] = __shfl(s, t0 + i);
        }
        ushort4 u[8];
#pragma unroll
        for (int i = 0; i < 8; i++)
            u[i] = *(const ushort4*)(h + (size_t)st[i] * 256 + lane * 4);
#pragma unroll
        for (int i = 0; i < 8; i++) {
            acc0 += pt[i] * bf2f(u[i].x);
            acc1 += pt[i] * bf2f(u[i].y);
            acc2 += pt[i] * bf2f(u[i].z);
            acc3 += pt[i] * bf2f(u[i].w);
        }
    }
    float inv = 1.f / (z + 1e-16f);
    float4 bv = ((const float4*)bias)[lane];
    ushort4 o;
    o.x = f2bf(fmaxf(acc0 * inv + bv.x, 0.f));
    o.y = f2bf(fmaxf(acc1 * inv + bv.y, 0.f));
    o.z = f2bf(fmaxf(acc2 * inv + bv.z, 0.f));
    o.w = f2bf(fmaxf(acc3 * inv + bv.w, 0.f));
    *(ushort4*)(out + (size_t)node * 256 + lane * 4) = o;
}

// fused mu/logstd: lanes 0..31 accumulate mu channels, 32..63 logstd channels.
__global__ __launch_bounds__(256) void aggregate_cat(const unsigned short* __restrict__ hcat,
                                                     const float* __restrict__ sm_s, const float* __restrict__ sm_d,
                                                     const float* __restrict__ sl_s, const float* __restrict__ sl_d,
                                                     const int* __restrict__ cnt,
                                                     const int* __restrict__ bucket,
                                                     const float* __restrict__ b_mu, const float* __restrict__ b_ls,
                                                     float* __restrict__ out_mu, float* __restrict__ out_ls, int N) {
    int wave = threadIdx.x >> 6, lane = threadIdx.x & 63;
    int node = blockIdx.x * 4 + wave;
    if (node >= N) return;
    int deg = min(cnt[node], 64);
    int base = node << 6;
    float sdm = sm_d[node], sdl = sl_d[node];
    bool isMu = lane < 32;
    bool valid = lane < deg;
    int s = valid ? bucket[base + lane] : 0;
    float eM = -INFINITY, eL = -INFINITY;
    if (valid) {
        float tM = sm_s[s] + sdm;
        eM = (tM > 0.f) ? tM : 0.2f * tM;
        float tL = sl_s[s] + sdl;
        eL = (tL > 0.f) ? tL : 0.2f * tL;
    }
    float mM = eM, mL = eL;
    for (int off = 32; off; off >>= 1) {
        mM = fmaxf(mM, __shfl_xor(mM, off));
        mL = fmaxf(mL, __shfl_xor(mL, off));
    }
    float pM = valid ? __expf(eM - mM) : 0.f;
    float pL = valid ? __expf(eL - mL) : 0.f;
    float zM = pM, zL = pL;
    for (int off = 32; off; off >>= 1) {
        zM += __shfl_xor(zM, off);
        zL += __shfl_xor(zL, off);
    }

    float acc0 = 0.f, acc1 = 0.f, acc2 = 0.f, acc3 = 0.f;
    int cnt8 = (deg + 7) & ~7;
    for (int t0 = 0; t0 < cnt8; t0 += 8) {
        float pt[8];
        int st[8];
#pragma unroll
        for (int i = 0; i < 8; i++) {
            float a = __shfl(pM, t0 + i);
            float b = __shfl(pL, t0 + i);
            pt[i] = isMu ? a : b;
            st[i] = __shfl(s, t0 + i);
        }
        ushort4 u[8];
#pragma unroll
        for (int i = 0; i < 8; i++)
            u[i] = *(const ushort4*)(hcat + (size_t)st[i] * 256 + lane * 4);
#pragma unroll
        for (int i = 0; i < 8; i++) {
            acc0 += pt[i] * bf2f(u[i].x);
            acc1 += pt[i] * bf2f(u[i].y);
            acc2 += pt[i] * bf2f(u[i].z);
            acc3 += pt[i] * bf2f(u[i].w);
        }
    }
    float inv = isMu ? (1.f / (zM + 1e-16f)) : (1.f / (zL + 1e-16f));
    int c = (lane & 31) * 4;
    float4 bv = *(const float4*)((isMu ? b_mu : b_ls) + c);
    float4 o = make_float4(acc0 * inv + bv.x, acc1 * inv + bv.y,
                           acc2 * inv + bv.z, acc3 * inv + bv.w);
    float* dstp = isMu ? (out_mu + (size_t)node * 128 + c) : (out_ls + (size_t)node * 128 + c);
    *(float4*)dstp = o;
}

// ---------------- launch ----------------

extern "C" void kernel_launch(void* const* d_in, const int* in_sizes, int n_in,
                              void* d_out, int out_size, void* d_ws, size_t ws_size,
                              hipStream_t stream) {
    const int N = NNODES;
    const float* x      = (const float*)d_in[0];
    const int*   ei     = (const int*)d_in[1];
    const int    E      = in_sizes[1] / 2;
    const int*   src    = ei;
    const int*   dst    = ei + E;
    const float* W1     = (const float*)d_in[2];
    const float* a_src1 = (const float*)d_in[3];
    const float* a_dst1 = (const float*)d_in[4];
    const float* b1     = (const float*)d_in[5];
    const float* W_mu   = (const float*)d_in[6];
    const float* a_src_mu = (const float*)d_in[7];
    const float* a_dst_mu = (const float*)d_in[8];
    const float* b_mu   = (const float*)d_in[9];
    const float* W_ls   = (const float*)d_in[10];
    const float* a_src_ls = (const float*)d_in[11];
    const float* a_dst_ls = (const float*)d_in[12];
    const float* b_ls   = (const float*)d_in[13];

    const size_t NM = (size_t)N * 256;   // 12.8M elems

    // workspace layout (16B-aligned blocks first)
    char* w = (char*)d_ws;
    unsigned short* hlin = (unsigned short*)w;              w += NM * 2;
    unsigned short* h    = (unsigned short*)w;              w += NM * 2;
    unsigned short* hcat = (unsigned short*)w;              w += NM * 2;
    unsigned short* W1t  = (unsigned short*)w;              w += 256 * 256 * 2;
    unsigned short* Wct  = (unsigned short*)w;              w += 256 * 256 * 2;
    // score arrays: contiguous 6N floats; (sms,sls) and (smd,sld) adjacent for
    // the halfsplit epilogue (target = base + half*N).
    float* s1s = (float*)w;  w += N * 4;
    float* s1d = (float*)w;  w += N * 4;
    float* sms = (float*)w;  w += N * 4;
    float* sls = (float*)w;  w += N * 4;
    float* smd = (float*)w;  w += N * 4;
    float* sld = (float*)w;  w += N * 4;
    float* acat_src = (float*)w;  w += 256 * 4;
    float* acat_dst = (float*)w;  w += 256 * 4;
    int* cnt = (int*)w;        w += N * 4;
    int* bucket = (int*)w;     w += (size_t)N * 64 * 4;   // 12.8MB

    const int egrid = (E + 255) / 256;
    const int ngrid4 = (N + 3) / 4;               // 12500
    const int mtiles = (N + 127) / 128;           // 391

    // ---- fused prep (W transposes + zero scores/cnt + acat) ----
    prep_kernel<<<1882, 256, 0, stream>>>(W1, W1t, W_mu, W_ls, Wct,
                                          s1s, cnt,
                                          a_src_mu, a_src_ls, a_dst_mu, a_dst_ls,
                                          acat_src, acat_dst, N);

    // ---- bucket build (single pass) ----
    scatter_direct<<<egrid, 256, 0, stream>>>(src, dst, E, cnt, bucket);

    // ---- layer 1: x -> h (relu); scores fused in GEMM epilogue ----
    mfma_gemm<true><<<dim3(mtiles, 2), 256, 0, stream>>>(x, W1t, hlin, a_src1, a_dst1,
                                                         s1s, s1d, 0, N, 256, 256);
    aggregate_l1<<<ngrid4, 256, 0, stream>>>(hlin, s1s, s1d, cnt, bucket, b1, h, N);

    // ---- fused mu/logstd head; scores fused (halfsplit) ----
    mfma_gemm<false><<<dim3(mtiles, 2), 256, 0, stream>>>(h, Wct, hcat, acat_src, acat_dst,
                                                          sms, smd, 1, N, 256, 256);
    float* out_mu = (float*)d_out;
    float* out_ls = out_mu + (size_t)N * 128;
    aggregate_cat<<<ngrid4, 256, 0, stream>>>(hcat, sms, smd, sls, sld, cnt, bucket,
                                              b_mu, b_ls, out_mu, out_ls, N);
}